// Round 8
// baseline (4725.460 us; speedup 1.0000x reference)
//
#include <hip/hip_runtime.h>
#include <hip/hip_bf16.h>
#include <hip/hip_cooperative_groups.h>
#include <math.h>

namespace cg = cooperative_groups;

#define B_    64
#define T_    24
#define IND_  25
#define HID_  64
#define NPIX  625

#define WP0 27
#define WP1 29
#define XP0 (WP0*WP0*32)      // 23,328 ush per (par,b) br0 x-plane
#define XP1 (WP1*WP1*32)      // 26,912
#define XB0R (2*64*XP0)       // 2,985,984 ush (br0 region, both parities)
#define XB1R (2*64*XP1)       // 3,444,736
#define XBTOT (XB0R+XB1R)     // 6,430,720 ush

#define HALSZ 7424            // bytes per bid (<= 2 rows x 3712)
#define HALTOT_USH (256*HALSZ/2)   // 950,272 ush

#define HCROWS 832
#define HCB (HCROWS*128)
#define HCTOT (B_*HCB)        // 6,815,744 ush

#define WFRAG_PER_BR (9*3*4*4*512)
#define WFRAG_TOT (2*WFRAG_PER_BR)   // 442,368 ush

// LDS geometry (bytes)
#define RBMAX 3712            // 29*128
#define HWIN_B (18*RBMAX)     // 66,816  (17 window rows + 1 margin)
#define DLY_B  (5*RBMAX)      // 18,560  (4 delay rows + margin)
#define XWIN_B (18*29*64)     // 33,408
#define LDS_B  (HWIN_B+DLY_B+XWIN_B) // 118,784

typedef __bf16 bf16x8 __attribute__((ext_vector_type(8)));
typedef float  f32x4  __attribute__((ext_vector_type(4)));
typedef unsigned short ushort_t;
typedef unsigned int   uint_t;

typedef const __attribute__((address_space(1))) void as1_cvoid;
typedef __attribute__((address_space(3))) void as3_void;

__device__ __forceinline__ float sigmoidf_(float x) { return 1.f / (1.f + __expf(-x)); }
__device__ __forceinline__ float tanh_fast(float x) { return 2.f / (1.f + __expf(-2.f * x)) - 1.f; }
__device__ __forceinline__ ushort_t f2bf(float f) {
    unsigned int u = __float_as_uint(f);
    u += 0x7FFFu + ((u >> 16) & 1u);
    return (ushort_t)(u >> 16);
}

__global__ __launch_bounds__(256) void fill_zero_kernel(uint_t* __restrict__ p, int n) {
    int i = blockIdx.x * 256 + threadIdx.x;
    if (i < n) p[i] = 0u;
}

// Wfrag[br][tap][kk][wm][mf][lane][e]: m = wm*64 + gate*16 + ocl, gate=mf, oc=wm*16+l16.
__global__ __launch_bounds__(256) void repack_w_kernel(
    const float* __restrict__ w1, const float* __restrict__ w2, ushort_t* __restrict__ Wfrag)
{
    int id = blockIdx.x * 256 + threadIdx.x;
    if (id >= WFRAG_TOT) return;
    int e    = id & 7;
    int lane = (id >> 3) & 63;
    int mf   = (id >> 9) & 3;
    int wm   = (id >> 11) & 3;
    int rest = id >> 13;
    int kk   = rest % 3;
    int tap  = (rest / 3) % 9;
    int br   = rest / 27;
    int l16 = lane & 15, kh = lane >> 4;
    int gate = mf;
    int oc   = wm * 16 + l16;
    int k    = kh * 8 + e;
    int c;
    if (kk == 0)      c = (k < IND_) ? k : -1;
    else if (kk == 1) c = IND_ + k;
    else              c = IND_ + 32 + k;
    const float* w = br ? w2 : w1;
    float v = (c >= 0) ? w[((size_t)(gate * 64 + oc) * 89 + c) * 9 + tap] : 0.f;
    Wfrag[id] = f2bf(v);
}

__global__ __launch_bounds__(256) void repack_wc_kernel(
    const float* __restrict__ wc, ushort_t* __restrict__ Wc)
{
    int id = blockIdx.x * 256 + threadIdx.x;
    if (id >= 9 * 64 * 128) return;
    int k   = id % 128;
    int oc  = (id / 128) % 64;
    int tap = id / (128 * 64);
    Wc[id] = f2bf(wc[((size_t)(oc * 128) + k) * 9 + tap]);
}

// ---------------- persistent cooperative ConvLSTM ----------------

__device__ __forceinline__ void ln_phase(
    const float* __restrict__ x, const float* __restrict__ gamma, const float* __restrict__ beta,
    ushort_t* __restrict__ xb, int tt, int bid, int tid)
{
    if (tid >= 157) return;
    const int p = bid * 157 + tid;
    if (p >= B_ * NPIX) return;
    const int bb = p / NPIX, hw = p - bb * NPIX;
    const int y = hw / 25, xx = hw - y * 25;
    const float* xp = x + ((size_t)(bb * T_ + tt) * IND_) * NPIX + hw;
    float v[IND_];
    float s = 0.f;
#pragma unroll
    for (int c = 0; c < IND_; ++c) { v[c] = xp[c * NPIX]; s += v[c]; }
    const float mu = s * (1.f / IND_);
    float ss = 0.f;
#pragma unroll
    for (int c = 0; c < IND_; ++c) { float dd = v[c] - mu; ss += dd * dd; }
    const float rstd = rsqrtf(ss * (1.f / IND_) + 1e-5f);
    ushort_t us[IND_];
#pragma unroll
    for (int c = 0; c < IND_; ++c) us[c] = f2bf((v[c] - mu) * rstd * gamma[c] + beta[c]);
    uint4 q0, q1, q2;
    q0.x = us[0] | ((uint_t)us[1] << 16);  q0.y = us[2] | ((uint_t)us[3] << 16);
    q0.z = us[4] | ((uint_t)us[5] << 16);  q0.w = us[6] | ((uint_t)us[7] << 16);
    q1.x = us[8] | ((uint_t)us[9] << 16);  q1.y = us[10] | ((uint_t)us[11] << 16);
    q1.z = us[12] | ((uint_t)us[13] << 16); q1.w = us[14] | ((uint_t)us[15] << 16);
    q2.x = us[16] | ((uint_t)us[17] << 16); q2.y = us[18] | ((uint_t)us[19] << 16);
    q2.z = us[20] | ((uint_t)us[21] << 16); q2.w = us[22] | ((uint_t)us[23] << 16);
    const int par = tt & 1;
    ushort_t* o0 = xb + ((size_t)par * 64 + bb) * XP0 + (size_t)((y + 1) * WP0 + (xx + 1)) * 32;
    ushort_t* o1 = xb + XB0R + ((size_t)par * 64 + bb) * XP1 + (size_t)((y + 2) * WP1 + (xx + 2)) * 32;
    *(uint4*)o0 = q0; *(uint4*)(o0 + 8) = q1; *(uint4*)(o0 + 16) = q2; o0[24] = us[24];
    *(uint4*)o1 = q0; *(uint4*)(o1 + 8) = q1; *(uint4*)(o1 + 16) = q2; o1[24] = us[24];
}

// One output row-tile: NF rows x 32 cols at own-row offset t0rel from rowlo.
// h from LDS window (XOR-swizzled) or delay rows; x from LDS x-window; writes new h
// into the window (+ boundary rows to partner's global halo image, pre-swizzled).
template<int NF>
__device__ __forceinline__ void conv_tile_p(
    int t0rel, int tidx, int d, int Wp, int RB, int XRB, int rowlo, int half,
    const ushort_t* __restrict__ WFb,
    const float* bi4, const float* bff4, const float* bo4, const float* bg4,
    char* hwin, char* dly, char* xwin, char* __restrict__ haloOut,
    f32x4 (&cc)[5], int tid)
{
    const int w    = tid >> 6, lane = tid & 63;
    const int wm   = w & 3, wn = w >> 2;
    const int l16  = lane & 15, kh = lane >> 4;

    int rit[NF], xxa[NF];
#pragma unroll
    for (int nf = 0; nf < NF; ++nf) {
        int m = wn * NF + nf;
        rit[nf] = m >> 1;
        xxa[nf] = ((m & 1) << 4) + l16;
    }

    f32x4 acc[4][NF];
#pragma unroll
    for (int i = 0; i < 4; ++i)
#pragma unroll
        for (int j = 0; j < NF; ++j) acc[i][j] = (f32x4){0.f, 0.f, 0.f, 0.f};

    for (int tap = 0; tap < 9; ++tap) {
        const int ky = tap / 3, kx = tap - 3 * ky;
        const int kyd = ky * d, kxd = kx * d;
        const ushort_t* __restrict__ WT = WFb + (size_t)(tap * 3) * 8192 + wm * 2048 + lane * 8;

        int slot[NF], col[NF];
        bool stale[NF];
#pragma unroll
        for (int nf = 0; nf < NF; ++nf) {
            slot[nf]  = t0rel + rit[nf] + kyd;
            col[nf]   = xxa[nf] + kxd;
            stale[nf] = (tidx > 0) && (ky == 0) && (rit[nf] < d);
        }
        // kk=0: x chunk (LDS x-window, no swizzle)
        {
            bf16x8 af[4], bq[NF];
#pragma unroll
            for (int mf = 0; mf < 4; ++mf) af[mf] = *(const bf16x8*)(WT + mf * 512);
#pragma unroll
            for (int nf = 0; nf < NF; ++nf)
                bq[nf] = *(const bf16x8*)(xwin + (size_t)slot[nf] * XRB + col[nf] * 64 + kh * 16);
#pragma unroll
            for (int mf = 0; mf < 4; ++mf)
#pragma unroll
                for (int nf = 0; nf < NF; ++nf)
                    acc[mf][nf] = __builtin_amdgcn_mfma_f32_16x16x32_bf16(
                        af[mf], bq[nf], acc[mf][nf], 0, 0, 0);
        }
        // kk=1,2: h chunks (LDS window or delay, XOR-swizzled)
#pragma unroll
        for (int kkh = 0; kkh < 2; ++kkh) {
            bf16x8 af[4], bq[NF];
#pragma unroll
            for (int mf = 0; mf < 4; ++mf)
                af[mf] = *(const bf16x8*)(WT + (size_t)(kkh + 1) * 8192 + mf * 512);
#pragma unroll
            for (int nf = 0; nf < NF; ++nf) {
                const int inrow = (col[nf] * 128 + kkh * 64 + kh * 16) ^ ((col[nf] & 7) << 4);
                const char* base = stale[nf]
                    ? (dly + (size_t)((tidx - 1) * d + rit[nf]) * RBMAX)
                    : (hwin + (size_t)slot[nf] * RB);
                bq[nf] = *(const bf16x8*)(base + inrow);
            }
#pragma unroll
            for (int mf = 0; mf < 4; ++mf)
#pragma unroll
                for (int nf = 0; nf < NF; ++nf)
                    acc[mf][nf] = __builtin_amdgcn_mfma_f32_16x16x32_bf16(
                        af[mf], bq[nf], acc[mf][nf], 0, 0, 0);
        }
    }

    __syncthreads();   // all reads of old h done before any write

    const int oc0 = wm * 16 + kh * 4;
#pragma unroll
    for (int nf = 0; nf < NF; ++nf) {
        if (xxa[nf] >= 25) continue;
        const int y = rowlo + t0rel + rit[nf];
        ushort_t hs[4];
#pragma unroll
        for (int r = 0; r < 4; ++r) {
            const float zi = acc[0][nf][r] + bi4[r];
            const float zf = acc[1][nf][r] + bff4[r];
            const float zo = acc[2][nf][r] + bo4[r];
            const float zg = acc[3][nf][r] + bg4[r];
            const float cn = sigmoidf_(zf) * cc[nf][r] + sigmoidf_(zi) * tanh_fast(zg);
            cc[nf][r] = cn;
            hs[r] = f2bf(sigmoidf_(zo) * tanh_fast(cn));
        }
        uint2 hv;
        hv.x = (uint_t)hs[0] | ((uint_t)hs[1] << 16);
        hv.y = (uint_t)hs[2] | ((uint_t)hs[3] << 16);
        const int c = xxa[nf] + d;
        const int inrow = (c * 128 + oc0 * 2) ^ ((c & 7) << 4);
        *(uint2*)(hwin + (size_t)(t0rel + rit[nf] + d) * RB + inrow) = hv;
        const bool send = (half == 0) ? (y >= 13 - d) : (y <= 12 + d);
        if (send) {
            const int j = (half == 0) ? (y - (13 - d)) : (y - 13);
            *(uint2*)(haloOut + (size_t)j * RB + inrow) = hv;
        }
    }
    __syncthreads();   // writes visible before next tile reads
}

// 256 blocks x 512 thr, 1/CU. Block = (br, b, row-half). h resident in LDS for all T;
// c resident in registers; only x window + d-row halo move per step.
__global__ __launch_bounds__(512, 2) void persist_kernel(
    const float* __restrict__ x, const float* __restrict__ ln_g, const float* __restrict__ ln_b,
    ushort_t* __restrict__ xb, char* __restrict__ haloG, const ushort_t* __restrict__ Wfrag,
    const float* __restrict__ b_l1, const float* __restrict__ b_l2,
    ushort_t* __restrict__ Hc)
{
    cg::grid_group grid = cg::this_grid();
    const int bid  = blockIdx.x, tid = threadIdx.x;
    const int br   = bid >> 7;
    const int b    = (bid >> 1) & 63;
    const int half = bid & 1;
    const int d    = 1 + br;
    const int Wp   = br ? WP1 : WP0;
    const int RB   = Wp * 128;
    const int XRB  = Wp * 64;
    const int rowlo = half ? 13 : 0;
    const int ny    = half ? 12 : 13;
    const int nrows = ny + 2 * d;
    const int haloslot0 = half ? 0 : (13 + d);
    const ushort_t* __restrict__ WFb = Wfrag + (size_t)br * WFRAG_PER_BR;
    const float* __restrict__ bias = br ? b_l2 : b_l1;
    char* __restrict__ haloOut = haloG + (size_t)(bid ^ 1) * HALSZ;

    __shared__ __align__(16) char LDSB[LDS_B];
    char* hwin = LDSB;
    char* dly  = LDSB + HWIN_B;
    char* xwin = LDSB + HWIN_B + DLY_B;

    for (int i = tid; i < LDS_B / 16; i += 512)
        *(uint4*)(LDSB + (size_t)i * 16) = (uint4){0u, 0u, 0u, 0u};

    const int lane = tid & 63;
    const int wm = (tid >> 6) & 3;
    const int kh = lane >> 4;
    const int oc0 = wm * 16 + kh * 4;
    float bi4[4], bff4[4], bo4[4], bg4[4];
#pragma unroll
    for (int r = 0; r < 4; ++r) {
        bi4[r]  = bias[oc0 + r];
        bff4[r] = bias[64 + oc0 + r];
        bo4[r]  = bias[128 + oc0 + r];
        bg4[r]  = bias[192 + oc0 + r];
    }

    f32x4 cA[5], cB[5], cC[5];
#pragma unroll
    for (int j = 0; j < 5; ++j) {
        cA[j] = (f32x4){0.f, 0.f, 0.f, 0.f};
        cB[j] = (f32x4){0.f, 0.f, 0.f, 0.f};
        cC[j] = (f32x4){0.f, 0.f, 0.f, 0.f};
    }

    ln_phase(x, ln_g, ln_b, xb, 0, bid, tid);
    grid.sync();

    const int wu = tid & 448;
    const ushort_t* xplane = (br == 0) ? (xb + (size_t)b * XP0)
                                       : (xb + XB0R + (size_t)b * XP1);
    const size_t xparstride = (br == 0) ? (size_t)64 * XP0 : (size_t)64 * XP1;

    for (int t = 0; t < T_; ++t) {
        const int par = t & 1;
        // stage x window (linear image)
        {
            const char* gsrc = (const char*)(xplane + (size_t)par * xparstride
                                             + (size_t)rowlo * Wp * 32);
            const int nch = nrows * Wp * 4;
#pragma unroll
            for (int j = 0; j < 4; ++j) {
                const int i = j * 512 + tid;
                if (i < nch)
                    __builtin_amdgcn_global_load_lds(
                        (as1_cvoid*)(gsrc + (size_t)i * 16),
                        (as3_void*)(xwin + (size_t)(j * 512 + wu) * 16), 16, 0, 0);
            }
        }
        // stage halo rows (pre-swizzled global image -> linear LDS)
        {
            const int i = tid;
            if (i < d * Wp * 8)
                __builtin_amdgcn_global_load_lds(
                    (as1_cvoid*)(haloG + (size_t)bid * HALSZ + (size_t)i * 16),
                    (as3_void*)(hwin + (size_t)haloslot0 * RB + (size_t)wu * 16), 16, 0, 0);
        }
        if (t + 1 < T_) ln_phase(x, ln_g, ln_b, xb, t + 1, bid, tid);
        __syncthreads();
        // save delay rows (old h that later tiles will need after earlier tiles overwrite)
        {
            const int nchd = 2 * d * Wp * 8;
            const int rowch = Wp * 8;
            for (int i = tid; i < nchd; i += 512) {
                const int row = i / rowch, inner = i - row * rowch;
                const int srcslot = (row < d) ? (5 + row) : (10 + row - d);
                uint4 v = *(const uint4*)(hwin + (size_t)srcslot * RB + (size_t)inner * 16);
                *(uint4*)(dly + (size_t)row * RBMAX + (size_t)inner * 16) = v;
            }
        }
        __syncthreads();

        conv_tile_p<5>(0, 0, d, Wp, RB, XRB, rowlo, half, WFb, bi4, bff4, bo4, bg4,
                       hwin, dly, xwin, haloOut, cA, tid);
        conv_tile_p<5>(5, 1, d, Wp, RB, XRB, rowlo, half, WFb, bi4, bff4, bo4, bg4,
                       hwin, dly, xwin, haloOut, cB, tid);
        if (half == 0)
            conv_tile_p<3>(10, 2, d, Wp, RB, XRB, rowlo, half, WFb, bi4, bff4, bo4, bg4,
                           hwin, dly, xwin, haloOut, cC, tid);
        else
            conv_tile_p<2>(10, 2, d, Wp, RB, XRB, rowlo, half, WFb, bi4, bff4, bo4, bg4,
                           hwin, dly, xwin, haloOut, cC, tid);
        grid.sync();
    }

    // write final h from LDS straight into Hc[b][(y+1)*27+(x+1)][br*64 + oc]
    const int nitems = ny * 25 * 16;
    for (int i = tid; i < nitems; i += 512) {
        const int ocq = i & 15;
        const int rest = i >> 4;
        const int xx = rest % 25;
        const int y  = rowlo + rest / 25;
        const int c  = xx + d;
        uint2 v = *(const uint2*)(hwin + (size_t)(y + d - rowlo) * RB
                                  + ((c * 128 + ocq * 8) ^ ((c & 7) << 4)));
        *(uint2*)(Hc + (size_t)b * HCB + (size_t)((y + 1) * 27 + (xx + 1)) * 128
                  + br * 64 + ocq * 4) = v;
    }
}

// ---------------- tail (proven R3-R7) ----------------

__global__ __launch_bounds__(512) void conv_mfma_kernel(
    const ushort_t* __restrict__ Hc, const ushort_t* __restrict__ Wc,
    const float* __restrict__ bc, float* __restrict__ conv_out)
{
    const int rg = blockIdx.x;
    const int b  = blockIdx.y;
    const ushort_t* __restrict__ Hb = Hc + (size_t)b * HCB;

    const int tid  = threadIdx.x;
    const int w    = tid >> 6, lane = tid & 63;
    const int wm   = w & 1, wn = w >> 1;
    const int l16  = lane & 15, kh = lane >> 4;
    const int koff = kh * 8;

    f32x4 acc[2][2];
#pragma unroll
    for (int i = 0; i < 2; ++i)
#pragma unroll
        for (int j = 0; j < 2; ++j) acc[i][j] = (f32x4){0.f, 0.f, 0.f, 0.f};

    int baserow[2];
#pragma unroll
    for (int nf = 0; nf < 2; ++nf) {
        int n = wn * 32 + nf * 16 + l16;
        baserow[nf] = (rg * 4 + (n >> 5)) * 27 + (n & 31);
    }
    const ushort_t* __restrict__ Wm = Wc + (size_t)(wm * 32 + l16) * 128 + koff;

    for (int tap = 0; tap < 9; ++tap) {
        const int ky = tap / 3, kx = tap - 3 * ky;
        const int toff = ky * 27 + kx;
        const ushort_t* __restrict__ Wt = Wm + (size_t)tap * (64 * 128);
        const ushort_t* Urow[2];
#pragma unroll
        for (int nf = 0; nf < 2; ++nf)
            Urow[nf] = Hb + (size_t)(baserow[nf] + toff) * 128 + koff;
#pragma unroll
        for (int kk = 0; kk < 4; ++kk) {
            bf16x8 af[2], bfr[2];
#pragma unroll
            for (int mf = 0; mf < 2; ++mf)
                af[mf] = *(const bf16x8*)(Wt + mf * 16 * 128 + kk * 32);
#pragma unroll
            for (int nf = 0; nf < 2; ++nf)
                bfr[nf] = *(const bf16x8*)(Urow[nf] + kk * 32);
#pragma unroll
            for (int mf = 0; mf < 2; ++mf)
#pragma unroll
                for (int nf = 0; nf < 2; ++nf)
                    acc[mf][nf] = __builtin_amdgcn_mfma_f32_16x16x32_bf16(
                        af[mf], bfr[nf], acc[mf][nf], 0, 0, 0);
        }
    }

#pragma unroll
    for (int mf = 0; mf < 2; ++mf) {
#pragma unroll
        for (int nf = 0; nf < 2; ++nf) {
            const int n = wn * 32 + nf * 16 + l16;
            const int xx = n & 31;
            if (xx >= 25) continue;
            const int y = rg * 4 + wn;
            if (y >= 25) continue;
#pragma unroll
            for (int r = 0; r < 4; ++r) {
                const int oc = wm * 32 + mf * 16 + kh * 4 + r;
                const float v = fmaxf(acc[mf][nf][r] + bc[oc], 0.f);
                conv_out[((size_t)(b * 64 + oc)) * NPIX + y * 25 + xx] = v;
            }
        }
    }
}

__global__ __launch_bounds__(256) void pool_kernel(
    const float* __restrict__ conv_out, float* __restrict__ pool)
{
    int id = blockIdx.x * 256 + threadIdx.x;
    if (id >= B_ * 64 * 144) return;
    int px = id % 12;
    int py = (id / 12) % 12;
    int oc = (id / 144) % 64;
    int b  = id / (144 * 64);
    const float* p = conv_out + ((size_t)(b * 64 + oc)) * NPIX;
    const int cy = 2 * py, cx = 2 * px;
    float mx = fmaxf(fmaxf(p[cy * 25 + cx], p[cy * 25 + cx + 1]),
                     fmaxf(p[(cy + 1) * 25 + cx], p[(cy + 1) * 25 + cx + 1]));
    pool[(size_t)b * 9216 + oc * 144 + py * 12 + px] = mx;
}

__global__ __launch_bounds__(256) void fc1_kernel(
    const float* __restrict__ pool, const float* __restrict__ w1, const float* __restrict__ b1,
    float* __restrict__ f1)
{
    const int task = blockIdx.x * 4 + (threadIdx.x >> 6);
    const int lane = threadIdx.x & 63;
    const int b = task >> 6, oc = task & 63;
    const float* pr = pool + (size_t)b * 9216;
    const float* wr = w1 + (size_t)oc * 9216;
    float acc = 0.f;
#pragma unroll 4
    for (int it = 0; it < 36; ++it) {
        const int k = it * 256 + lane * 4;
        const float4 p = *(const float4*)(pr + k);
        const float4 ww = *(const float4*)(wr + k);
        acc += p.x * ww.x + p.y * ww.y + p.z * ww.z + p.w * ww.w;
    }
#pragma unroll
    for (int off = 32; off > 0; off >>= 1) acc += __shfl_down(acc, off);
    if (lane == 0) f1[b * 64 + oc] = fmaxf(acc + b1[oc], 0.f);
}

__global__ __launch_bounds__(64) void head2_kernel(
    const float* __restrict__ f1,
    const float* __restrict__ w2, const float* __restrict__ b2,
    const float* __restrict__ w3, const float* __restrict__ b3,
    float* __restrict__ out)
{
    const int b = blockIdx.x;
    __shared__ float f1l[64];
    __shared__ float f2[32];
    const int tid = threadIdx.x;
    f1l[tid] = f1[b * 64 + tid];
    __syncthreads();
    if (tid < 32) {
        float acc = b2[tid];
        const float* wr = w2 + (size_t)tid * 64;
#pragma unroll
        for (int k = 0; k < 64; ++k) acc += f1l[k] * wr[k];
        f2[tid] = fmaxf(acc, 0.f);
    }
    __syncthreads();
    if (tid == 0) {
        float y0 = b3[0], y1 = b3[1];
#pragma unroll
        for (int k = 0; k < 32; ++k) { y0 += f2[k] * w3[k]; y1 += f2[k] * w3[32 + k]; }
        const float m = fmaxf(y0, y1);
        const float lse = m + logf(expf(y0 - m) + expf(y1 - m));
        out[b * 2 + 0] = y0 - lse;
        out[b * 2 + 1] = y1 - lse;
    }
}

extern "C" void kernel_launch(void* const* d_in, const int* in_sizes, int n_in,
                              void* d_out, int out_size, void* d_ws, size_t ws_size,
                              hipStream_t stream) {
    const float* x    = (const float*)d_in[0];
    const float* ln_g = (const float*)d_in[1];
    const float* ln_b = (const float*)d_in[2];
    const float* w_l1 = (const float*)d_in[3];
    const float* b_l1 = (const float*)d_in[4];
    const float* w_l2 = (const float*)d_in[5];
    const float* b_l2 = (const float*)d_in[6];
    const float* w_c  = (const float*)d_in[7];
    const float* b_c  = (const float*)d_in[8];
    const float* w_f1 = (const float*)d_in[9];
    const float* b_f1 = (const float*)d_in[10];
    const float* w_f2 = (const float*)d_in[11];
    const float* b_f2 = (const float*)d_in[12];
    const float* w_f3 = (const float*)d_in[13];
    const float* b_f3 = (const float*)d_in[14];

    // ws layout (ush offsets):
    //   xb   @0:           6,430,720   (LN'd x, both branches x both parities)
    //   halo @6,430,720:     950,272   (256 x 7424B pre-swizzled halo images)
    //   Hc   @7,380,992:   6,815,744   (final-conv input; borders zero-filled)
    //   Wfrag@14,196,736:    442,368 | Wc: 73,728 | f1: 8,192
    //   tail aliases: conv_out+pool -> xb region (dead after persist).
    // Total ~29.4 MB.
    ushort_t* wsu = (ushort_t*)d_ws;
    uint_t*   wsi = (uint_t*)d_ws;

    ushort_t* xb    = wsu;
    char*     haloG = (char*)(wsu + XBTOT);
    ushort_t* Hc    = wsu + XBTOT + HALTOT_USH;
    ushort_t* Wfrag = wsu + XBTOT + HALTOT_USH + HCTOT;
    ushort_t* Wc    = Wfrag + WFRAG_TOT;
    float*    f1    = (float*)(Wc + 73728);
    float*    conv_out = (float*)wsu;
    float*    pool  = (float*)wsu + 2560000;

    // zero xb (borders) + halo (t=0 zeros) + Hc (borders) every launch
    const int n_fill = (XBTOT + HALTOT_USH + HCTOT) / 2;
    fill_zero_kernel<<<(n_fill + 255) / 256, 256, 0, stream>>>(wsi, n_fill);
    repack_w_kernel<<<(WFRAG_TOT + 255) / 256, 256, 0, stream>>>(w_l1, w_l2, Wfrag);
    repack_wc_kernel<<<(9 * 64 * 128 + 255) / 256, 256, 0, stream>>>(w_c, Wc);

    void* kargs[9];
    kargs[0] = (void*)&x;    kargs[1] = (void*)&ln_g;  kargs[2] = (void*)&ln_b;
    kargs[3] = (void*)&xb;   kargs[4] = (void*)&haloG; kargs[5] = (void*)&Wfrag;
    kargs[6] = (void*)&b_l1; kargs[7] = (void*)&b_l2;  kargs[8] = (void*)&Hc;
    hipLaunchCooperativeKernel((void*)persist_kernel, dim3(256), dim3(512), kargs, 0, stream);

    conv_mfma_kernel<<<dim3(7, B_), 512, 0, stream>>>(Hc, Wc, b_c, conv_out);
    pool_kernel<<<(B_ * 64 * 144 + 255) / 256, 256, 0, stream>>>(conv_out, pool);
    fc1_kernel<<<1024, 256, 0, stream>>>(pool, w_f1, b_f1, f1);
    head2_kernel<<<B_, 64, 0, stream>>>(f1, w_f2, b_f2, w_f3, b_f3, (float*)d_out);
}

// Round 9
// 4318.822 us; speedup vs baseline: 1.0942x; 1.0942x over previous
//
#include <hip/hip_runtime.h>
#include <hip/hip_bf16.h>
#include <math.h>

#define B_    64
#define T_    24
#define IND_  25
#define HID_  64
#define NPIX  625

// padded-grid geometry
#define WP0   27
#define WP1   29
#define XSTR  32          // x-buf pixel stride (ushorts)
#define HSTR  72          // h-buf pixel stride (ushorts)
#define XROWS0 744
#define XROWS1 856
#define HROWS0 744
#define HROWS1 856
#define XB0   (XROWS0*XSTR)
#define XB1   (XROWS1*XSTR)
#define HB0   (HROWS0*HSTR)
#define HB1   (HROWS1*HSTR)
#define XB0T  (B_*XB0)        // 1,523,712
#define XB1T  (B_*XB1)        // 1,753,088
#define HB0T  (B_*HB0)        // 3,428,352
#define HB1T  (B_*HB1)        // 3,944,448
#define HPART (HB0T+HB1T)     // 7,372,800 per parity

// staged pixels / 16B chunks per branch
#define RST0  200
#define RST1  272
#define CH0   (RST0*9)    // 1800
#define CH1   (RST1*9)    // 2448

// final-conv combined input: [b][832 rows][128] bf16
#define HCROWS 832
#define HCB    (HCROWS*128)
#define HCTOT  (B_*HCB)

#define WFRAG_PER_BR (9*3*4*4*512)    // 221,184
#define WFRAG_TOT    (2*WFRAG_PER_BR)

typedef __bf16 bf16x8 __attribute__((ext_vector_type(8)));
typedef float  f32x4  __attribute__((ext_vector_type(4)));
typedef unsigned short ushort_t;
typedef unsigned int   uint_t;

typedef const __attribute__((address_space(1))) void as1_cvoid;
typedef __attribute__((address_space(3))) void as3_void;

__device__ __forceinline__ float sigmoidf_(float x) { return 1.f / (1.f + __expf(-x)); }
__device__ __forceinline__ float tanh_fast(float x) { return 2.f / (1.f + __expf(-2.f * x)) - 1.f; }
__device__ __forceinline__ ushort_t f2bf(float f) {
    unsigned int u = __float_as_uint(f);
    u += 0x7FFFu + ((u >> 16) & 1u);
    return (ushort_t)(u >> 16);
}

__global__ __launch_bounds__(256) void fill_zero_kernel(uint_t* __restrict__ p, int n) {
    int i = blockIdx.x * 256 + threadIdx.x;
    if (i < n) p[i] = 0u;
}

// Wfrag[br][tap][kk][wm][mf][lane][e]: m = wm*64 + gate*16 + ocl, gate=mf, oc=wm*16+l16.
__global__ __launch_bounds__(256) void repack_w_kernel(
    const float* __restrict__ w1, const float* __restrict__ w2, ushort_t* __restrict__ Wfrag)
{
    int id = blockIdx.x * 256 + threadIdx.x;
    if (id >= WFRAG_TOT) return;
    int e    = id & 7;
    int lane = (id >> 3) & 63;
    int mf   = (id >> 9) & 3;
    int wm   = (id >> 11) & 3;
    int rest = id >> 13;
    int kk   = rest % 3;
    int tap  = (rest / 3) % 9;
    int br   = rest / 27;
    int l16 = lane & 15, kh = lane >> 4;
    int gate = mf;
    int oc   = wm * 16 + l16;
    int k    = kh * 8 + e;
    int c;
    if (kk == 0)      c = (k < IND_) ? k : -1;
    else if (kk == 1) c = IND_ + k;
    else              c = IND_ + 32 + k;
    const float* w = br ? w2 : w1;
    float v = (c >= 0) ? w[((size_t)(gate * 64 + oc) * 89 + c) * 9 + tap] : 0.f;
    Wfrag[id] = f2bf(v);
}

__global__ __launch_bounds__(256) void repack_wc_kernel(
    const float* __restrict__ wc, ushort_t* __restrict__ Wc)
{
    int id = blockIdx.x * 256 + threadIdx.x;
    if (id >= 9 * 64 * 128) return;
    int k   = id % 128;
    int oc  = (id / 128) % 64;
    int tap = id / (128 * 64);
    Wc[id] = f2bf(wc[((size_t)(oc * 128) + k) * 9 + tap]);
}

// LayerNorm for timestep t -> bf16 into both branches' x-bufs ([row][32] layout).
__global__ __launch_bounds__(256) void ln_t_kernel(
    const float* __restrict__ x, const float* __restrict__ gamma, const float* __restrict__ beta,
    ushort_t* __restrict__ xb0, ushort_t* __restrict__ xb1, int t)
{
    int p = blockIdx.x * 256 + threadIdx.x;
    if (p >= B_ * NPIX) return;
    int b = p / NPIX, hw = p % NPIX;
    int y = hw / 25, xx = hw % 25;
    const float* xp = x + ((size_t)(b * T_ + t) * IND_) * NPIX + hw;
    float v[IND_];
    float s = 0.f;
#pragma unroll
    for (int c = 0; c < IND_; ++c) { v[c] = xp[c * NPIX]; s += v[c]; }
    float mu = s * (1.f / IND_);
    float ss = 0.f;
#pragma unroll
    for (int c = 0; c < IND_; ++c) { float d = v[c] - mu; ss += d * d; }
    float rstd = rsqrtf(ss * (1.f / IND_) + 1e-5f);
    ushort_t* o0 = xb0 + (size_t)b * XB0 + (size_t)((y + 1) * WP0 + (xx + 1)) * XSTR;
    ushort_t* o1 = xb1 + (size_t)b * XB1 + (size_t)((y + 2) * WP1 + (xx + 2)) * XSTR;
#pragma unroll
    for (int c = 0; c < IND_; ++c) {
        ushort_t hv = f2bf((v[c] - mu) * rstd * gamma[c] + beta[c]);
        o0[c] = hv;
        o1[c] = hv;
    }
}

// One ConvLSTM timestep, both branches. h-tile async-staged into LDS via
// global_load_lds; x B-fragments from global; c in coalesced f32x4 layout.
__global__ __launch_bounds__(512, 4) void convlstm_mfma_kernel(
    const ushort_t* __restrict__ xb0g, const ushort_t* __restrict__ xb1g,
    const ushort_t* __restrict__ h0c, const ushort_t* __restrict__ h1c,
    ushort_t* __restrict__ h0n, ushort_t* __restrict__ h1n,
    const ushort_t* __restrict__ Wfrag,
    const float* __restrict__ bias1, const float* __restrict__ bias2,
    float* __restrict__ cst, int t)
{
    const int rg = blockIdx.x;
    const int b  = blockIdx.y;
    const int br = blockIdx.z;
    const int d  = 1 + br;
    const int Wp = 25 + 2 * d;
    const ushort_t* __restrict__ xb = (br ? xb1g + (size_t)b * XB1 : xb0g + (size_t)b * XB0);
    const ushort_t* __restrict__ hc = (br ? h1c + (size_t)b * HB1 : h0c + (size_t)b * HB0);
    ushort_t* __restrict__ hn       = (br ? h1n + (size_t)b * HB1 : h0n + (size_t)b * HB0);
    const float* __restrict__ bias = br ? bias2 : bias1;
    const ushort_t* __restrict__ WFb = Wfrag + (size_t)br * WFRAG_PER_BR;
    // c layout: [(br*B+b)][ocq=16][pix] of f32x4
    f32x4* __restrict__ cb4 = (f32x4*)cst + (size_t)(br * B_ + b) * 16 * NPIX;

    __shared__ ushort_t tile[RST1 * HSTR];   // 39,168 B

    const int tid = threadIdx.x;
    const int u0  = rg * 5 * Wp;
    const int CH  = br ? CH1 : CH0;

    // ---- async stage h-tile: pure linear 16B-chunk copy, no VGPR round-trip
    {
        const char* gsrc = (const char*)(hc + (size_t)u0 * HSTR);
        const int wave_u = tid & 448;   // w*64
#pragma unroll
        for (int j = 0; j < 5; ++j) {
            const int i = j * 512 + tid;
            if (i < CH) {
                __builtin_amdgcn_global_load_lds(
                    (as1_cvoid*)(gsrc + (size_t)i * 16),
                    (as3_void*)((char*)tile + (size_t)(j * 512 + wave_u) * 16),
                    16, 0, 0);
            }
        }
    }
    __syncthreads();

    const int w    = tid >> 6, lane = tid & 63;
    const int wm   = w & 3, wn = w >> 2;
    const int l16  = lane & 15, kh = lane >> 4;
    const int koff = kh * 8;

    f32x4 acc[4][5];
#pragma unroll
    for (int i = 0; i < 4; ++i)
#pragma unroll
        for (int j = 0; j < 5; ++j) acc[i][j] = (f32x4){0.f, 0.f, 0.f, 0.f};

    int baserel[5];
#pragma unroll
    for (int nf = 0; nf < 5; ++nf) {
        int n = wn * 80 + nf * 16 + l16;
        baserel[nf] = (n >> 5) * Wp + (n & 31);
    }

#pragma unroll 3
    for (int tap = 0; tap < 9; ++tap) {
        const int ky = tap / 3, kx = tap - 3 * ky;
        const int toff = (ky * Wp + kx) * d;
        const ushort_t* __restrict__ WT = WFb + (size_t)(tap * 3) * 8192 + wm * 2048 + lane * 8;
        // kk=0: x from global x-buf
        {
            bf16x8 af[4], bfr[5];
#pragma unroll
            for (int mf = 0; mf < 4; ++mf)
                af[mf] = *(const bf16x8*)(WT + mf * 512);
#pragma unroll
            for (int nf = 0; nf < 5; ++nf)
                bfr[nf] = *(const bf16x8*)(xb + (size_t)(u0 + baserel[nf] + toff) * XSTR + koff);
#pragma unroll
            for (int mf = 0; mf < 4; ++mf)
#pragma unroll
                for (int nf = 0; nf < 5; ++nf)
                    acc[mf][nf] = __builtin_amdgcn_mfma_f32_16x16x32_bf16(
                        af[mf], bfr[nf], acc[mf][nf], 0, 0, 0);
        }
        // kk=1,2: h from LDS
#pragma unroll
        for (int kkh = 0; kkh < 2; ++kkh) {
            bf16x8 af[4], bfr[5];
#pragma unroll
            for (int mf = 0; mf < 4; ++mf)
                af[mf] = *(const bf16x8*)(WT + (size_t)(kkh + 1) * 8192 + mf * 512);
#pragma unroll
            for (int nf = 0; nf < 5; ++nf)
                bfr[nf] = *(const bf16x8*)(tile + (baserel[nf] + toff) * HSTR + kkh * 32 + koff);
#pragma unroll
            for (int mf = 0; mf < 4; ++mf)
#pragma unroll
                for (int nf = 0; nf < 5; ++nf)
                    acc[mf][nf] = __builtin_amdgcn_mfma_f32_16x16x32_bf16(
                        af[mf], bfr[nf], acc[mf][nf], 0, 0, 0);
        }
    }

    // Epilogue: gates are mf (0..3); C/D reg r -> oc = wm*16 + kh*4 + r.
    const int oc0 = wm * 16 + kh * 4;
    const int ocq = wm * 4 + kh;
    float bi4[4], bf4[4], bo4[4], bg4[4];
#pragma unroll
    for (int r = 0; r < 4; ++r) {
        bi4[r] = bias[oc0 + r];
        bf4[r] = bias[64 + oc0 + r];
        bo4[r] = bias[128 + oc0 + r];
        bg4[r] = bias[192 + oc0 + r];
    }
#pragma unroll
    for (int nf = 0; nf < 5; ++nf) {
        const int n = wn * 80 + nf * 16 + l16;
        const int xx = n & 31;
        if (xx >= 25) continue;
        const int y = rg * 5 + (n >> 5);
        const int pix = y * 25 + xx;
        f32x4* cp = cb4 + (size_t)ocq * NPIX + pix;
        f32x4 cv;
        if (t != 0) cv = *cp;
        else        cv = (f32x4){0.f, 0.f, 0.f, 0.f};
        ushort_t hs[4];
#pragma unroll
        for (int r = 0; r < 4; ++r) {
            const float zi = acc[0][nf][r] + bi4[r];
            const float zf = acc[1][nf][r] + bf4[r];
            const float zo = acc[2][nf][r] + bo4[r];
            const float zg = acc[3][nf][r] + bg4[r];
            const float cn = sigmoidf_(zf) * cv[r] + sigmoidf_(zi) * tanh_fast(zg);
            cv[r] = cn;
            hs[r] = f2bf(sigmoidf_(zo) * tanh_fast(cn));
        }
        *cp = cv;
        uint2 hv;
        hv.x = (uint_t)hs[0] | ((uint_t)hs[1] << 16);
        hv.y = (uint_t)hs[2] | ((uint_t)hs[3] << 16);
        *(uint2*)(hn + (size_t)((y + d) * Wp + (xx + d)) * HSTR + oc0) = hv;
    }
}

// Combine final hidden states into Hc[b][(y+1)*27+(x+1)][k=128] bf16.
__global__ __launch_bounds__(256) void combine_h_kernel(
    const ushort_t* __restrict__ h0, const ushort_t* __restrict__ h1, ushort_t* __restrict__ Hc)
{
    int id = blockIdx.x * 256 + threadIdx.x;
    if (id >= B_ * NPIX * 128) return;
    int k   = id % 128;
    int pix = (id / 128) % NPIX;
    int b   = id / (128 * NPIX);
    int y = pix / 25, xx = pix % 25;
    ushort_t v;
    if (k < 64) v = h0[(size_t)b * HB0 + (size_t)((y + 1) * WP0 + (xx + 1)) * HSTR + k];
    else        v = h1[(size_t)b * HB1 + (size_t)((y + 2) * WP1 + (xx + 2)) * HSTR + (k - 64)];
    Hc[(size_t)b * HCB + (size_t)((y + 1) * 27 + (xx + 1)) * 128 + k] = v;
}

// Final 3x3 conv (128->64, pad 1) + bias + ReLU via MFMA implicit-GEMM.
__global__ __launch_bounds__(512) void conv_mfma_kernel(
    const ushort_t* __restrict__ Hc, const ushort_t* __restrict__ Wc,
    const float* __restrict__ bc, float* __restrict__ conv_out)
{
    const int rg = blockIdx.x;
    const int b  = blockIdx.y;
    const ushort_t* __restrict__ Hb = Hc + (size_t)b * HCB;

    const int tid  = threadIdx.x;
    const int w    = tid >> 6, lane = tid & 63;
    const int wm   = w & 1, wn = w >> 1;
    const int l16  = lane & 15, kh = lane >> 4;
    const int koff = kh * 8;

    f32x4 acc[2][2];
#pragma unroll
    for (int i = 0; i < 2; ++i)
#pragma unroll
        for (int j = 0; j < 2; ++j) acc[i][j] = (f32x4){0.f, 0.f, 0.f, 0.f};

    int baserow[2];
#pragma unroll
    for (int nf = 0; nf < 2; ++nf) {
        int n = wn * 32 + nf * 16 + l16;
        baserow[nf] = (rg * 4 + (n >> 5)) * 27 + (n & 31);
    }
    const ushort_t* __restrict__ Wm = Wc + (size_t)(wm * 32 + l16) * 128 + koff;

    for (int tap = 0; tap < 9; ++tap) {
        const int ky = tap / 3, kx = tap - 3 * ky;
        const int toff = ky * 27 + kx;
        const ushort_t* __restrict__ Wt = Wm + (size_t)tap * (64 * 128);
        const ushort_t* Urow[2];
#pragma unroll
        for (int nf = 0; nf < 2; ++nf)
            Urow[nf] = Hb + (size_t)(baserow[nf] + toff) * 128 + koff;
#pragma unroll
        for (int kk = 0; kk < 4; ++kk) {
            bf16x8 af[2], bfr[2];
#pragma unroll
            for (int mf = 0; mf < 2; ++mf)
                af[mf] = *(const bf16x8*)(Wt + mf * 16 * 128 + kk * 32);
#pragma unroll
            for (int nf = 0; nf < 2; ++nf)
                bfr[nf] = *(const bf16x8*)(Urow[nf] + kk * 32);
#pragma unroll
            for (int mf = 0; mf < 2; ++mf)
#pragma unroll
                for (int nf = 0; nf < 2; ++nf)
                    acc[mf][nf] = __builtin_amdgcn_mfma_f32_16x16x32_bf16(
                        af[mf], bfr[nf], acc[mf][nf], 0, 0, 0);
        }
    }

#pragma unroll
    for (int mf = 0; mf < 2; ++mf) {
#pragma unroll
        for (int nf = 0; nf < 2; ++nf) {
            const int n = wn * 32 + nf * 16 + l16;
            const int xx = n & 31;
            if (xx >= 25) continue;
            const int y = rg * 4 + wn;
            if (y >= 25) continue;
#pragma unroll
            for (int r = 0; r < 4; ++r) {
                const int oc = wm * 32 + mf * 16 + kh * 4 + r;
                const float v = fmaxf(acc[mf][nf][r] + bc[oc], 0.f);
                conv_out[((size_t)(b * 64 + oc)) * NPIX + y * 25 + xx] = v;
            }
        }
    }
}

__global__ __launch_bounds__(256) void pool_kernel(
    const float* __restrict__ conv_out, float* __restrict__ pool)
{
    int id = blockIdx.x * 256 + threadIdx.x;
    if (id >= B_ * 64 * 144) return;
    int px = id % 12;
    int py = (id / 12) % 12;
    int oc = (id / 144) % 64;
    int b  = id / (144 * 64);
    const float* p = conv_out + ((size_t)(b * 64 + oc)) * NPIX;
    const int cy = 2 * py, cx = 2 * px;
    float mx = fmaxf(fmaxf(p[cy * 25 + cx], p[cy * 25 + cx + 1]),
                     fmaxf(p[(cy + 1) * 25 + cx], p[(cy + 1) * 25 + cx + 1]));
    pool[(size_t)b * 9216 + oc * 144 + py * 12 + px] = mx;
}

__global__ __launch_bounds__(256) void fc1_kernel(
    const float* __restrict__ pool, const float* __restrict__ w1, const float* __restrict__ b1,
    float* __restrict__ f1)
{
    const int task = blockIdx.x * 4 + (threadIdx.x >> 6);
    const int lane = threadIdx.x & 63;
    const int b = task >> 6, oc = task & 63;
    const float* pr = pool + (size_t)b * 9216;
    const float* wr = w1 + (size_t)oc * 9216;
    float acc = 0.f;
#pragma unroll 4
    for (int it = 0; it < 36; ++it) {
        const int k = it * 256 + lane * 4;
        const float4 p = *(const float4*)(pr + k);
        const float4 ww = *(const float4*)(wr + k);
        acc += p.x * ww.x + p.y * ww.y + p.z * ww.z + p.w * ww.w;
    }
#pragma unroll
    for (int off = 32; off > 0; off >>= 1) acc += __shfl_down(acc, off);
    if (lane == 0) f1[b * 64 + oc] = fmaxf(acc + b1[oc], 0.f);
}

__global__ __launch_bounds__(64) void head2_kernel(
    const float* __restrict__ f1,
    const float* __restrict__ w2, const float* __restrict__ b2,
    const float* __restrict__ w3, const float* __restrict__ b3,
    float* __restrict__ out)
{
    const int b = blockIdx.x;
    __shared__ float f1l[64];
    __shared__ float f2[32];
    const int tid = threadIdx.x;
    f1l[tid] = f1[b * 64 + tid];
    __syncthreads();
    if (tid < 32) {
        float acc = b2[tid];
        const float* wr = w2 + (size_t)tid * 64;
#pragma unroll
        for (int k = 0; k < 64; ++k) acc += f1l[k] * wr[k];
        f2[tid] = fmaxf(acc, 0.f);
    }
    __syncthreads();
    if (tid == 0) {
        float y0 = b3[0], y1 = b3[1];
#pragma unroll
        for (int k = 0; k < 32; ++k) { y0 += f2[k] * w3[k]; y1 += f2[k] * w3[32 + k]; }
        const float m = fmaxf(y0, y1);
        const float lse = m + logf(expf(y0 - m) + expf(y1 - m));
        out[b * 2 + 0] = y0 - lse;
        out[b * 2 + 1] = y1 - lse;
    }
}

extern "C" void kernel_launch(void* const* d_in, const int* in_sizes, int n_in,
                              void* d_out, int out_size, void* d_ws, size_t ws_size,
                              hipStream_t stream) {
    const float* x    = (const float*)d_in[0];
    const float* ln_g = (const float*)d_in[1];
    const float* ln_b = (const float*)d_in[2];
    const float* w_l1 = (const float*)d_in[3];
    const float* b_l1 = (const float*)d_in[4];
    const float* w_l2 = (const float*)d_in[5];
    const float* b_l2 = (const float*)d_in[6];
    const float* w_c  = (const float*)d_in[7];
    const float* b_c  = (const float*)d_in[8];
    const float* w_f1 = (const float*)d_in[9];
    const float* b_f1 = (const float*)d_in[10];
    const float* w_f2 = (const float*)d_in[11];
    const float* b_f2 = (const float*)d_in[12];
    const float* w_f3 = (const float*)d_in[13];
    const float* b_f3 = (const float*)d_in[14];

    // Workspace (ushort offsets), identical to R5:
    //   xb0 @0 | xb1 | h0A | h1A | h0B | h1B -> UEND = 18,022,400 ush
    //   cst fp32 @UEND (5,120,000 f, f32x4 coalesced layout); conv_out+pool alias after loop
    //   Wfrag; Wc; f1. Hc aliases h0B/h1B half? (B half dead at end -> Hc)
    const size_t UEND = (size_t)XB0T + XB1T + 2 * ((size_t)HB0T + HB1T);
    ushort_t* wsu = (ushort_t*)d_ws;
    uint_t*   wsi = (uint_t*)d_ws;

    ushort_t* xb0 = wsu;
    ushort_t* xb1 = xb0 + XB0T;
    ushort_t* h0A = xb1 + XB1T;
    ushort_t* h1A = h0A + HB0T;
    ushort_t* h0B = h1A + HB1T;
    ushort_t* h1B = h0B + HB0T;
    float*    cst = (float*)(wsu + UEND);
    float*    conv_out = cst;
    float*    pool = cst + 2560000;
    ushort_t* Wfrag = wsu + UEND + 10240000;
    ushort_t* Wc    = Wfrag + WFRAG_TOT;
    float*    f1    = (float*)(Wc + 73728);
    ushort_t* Hc    = h0B;

    // zero x-bufs + h-bufs (borders + h0 state). cst handled via t==0 skip-read.
    fill_zero_kernel<<<((int)(UEND / 2) + 255) / 256, 256, 0, stream>>>(wsi, (int)(UEND / 2));
    repack_w_kernel<<<(WFRAG_TOT + 255) / 256, 256, 0, stream>>>(w_l1, w_l2, Wfrag);
    repack_wc_kernel<<<(9 * 64 * 128 + 255) / 256, 256, 0, stream>>>(w_c, Wc);

    ushort_t* H0[2] = {h0A, h0B};
    ushort_t* H1[2] = {h1A, h1B};
    for (int t = 0; t < T_; ++t) {
        const int cur = t & 1, nxt = cur ^ 1;
        ln_t_kernel<<<(B_ * NPIX + 255) / 256, 256, 0, stream>>>(x, ln_g, ln_b, xb0, xb1, t);
        convlstm_mfma_kernel<<<dim3(5, B_, 2), 512, 0, stream>>>(
            xb0, xb1, H0[cur], H1[cur], H0[nxt], H1[nxt], Wfrag, b_l1, b_l2, cst, t);
    }
    // final h in parity-0 (A). Hc overwrites dead B half: zero it first.
    fill_zero_kernel<<<(HCTOT / 2 + 255) / 256, 256, 0, stream>>>((uint_t*)Hc, HCTOT / 2);
    combine_h_kernel<<<(B_ * NPIX * 128 + 255) / 256, 256, 0, stream>>>(h0A, h1A, Hc);
    conv_mfma_kernel<<<dim3(7, B_), 512, 0, stream>>>(Hc, Wc, b_c, conv_out);
    pool_kernel<<<(B_ * 64 * 144 + 255) / 256, 256, 0, stream>>>(conv_out, pool);
    fc1_kernel<<<1024, 256, 0, stream>>>(pool, w_f1, b_f1, f1);
    head2_kernel<<<B_, 64, 0, stream>>>(f1, w_f2, b_f2, w_f3, b_f3, (float*)d_out);
}

// Round 10
// 1980.944 us; speedup vs baseline: 2.3855x; 2.1802x over previous
//
#include <hip/hip_runtime.h>
#include <hip/hip_bf16.h>
#include <math.h>

#define B_    64
#define T_    24
#define IND_  25
#define HID_  64
#define NPIX  625

// padded-grid geometry
#define WP0   27
#define WP1   29
#define XSTR  32          // x-buf pixel stride (ushorts)
#define HSTR  72          // h-buf pixel stride (ushorts)
#define XROWS0 744
#define XROWS1 856
#define HROWS0 744
#define HROWS1 856
#define XB0   (XROWS0*XSTR)
#define XB1   (XROWS1*XSTR)
#define HB0   (HROWS0*HSTR)
#define HB1   (HROWS1*HSTR)
#define XB0T  (B_*XB0)        // 1,523,712 per parity
#define XB1T  (B_*XB1)        // 1,753,088
#define HB0T  (B_*HB0)        // 3,428,352
#define HB1T  (B_*HB1)        // 3,944,448
#define HPART (HB0T+HB1T)     // 7,372,800 per parity

// staged pixels / 16B chunks per branch
#define RST0  200
#define RST1  272
#define CH0   (RST0*9)    // 1800  h chunks
#define CH1   (RST1*9)    // 2448
#define XCH0  (RST0*4)    // 800   x chunks
#define XCH1  (RST1*4)    // 1088

// final-conv combined input: [b][832 rows][128] bf16
#define HCROWS 832
#define HCB    (HCROWS*128)
#define HCTOT  (B_*HCB)

#define WFRAG_PER_BR (9*3*4*4*512)    // 221,184
#define WFRAG_TOT    (2*WFRAG_PER_BR)

typedef __bf16 bf16x8 __attribute__((ext_vector_type(8)));
typedef float  f32x4  __attribute__((ext_vector_type(4)));
typedef unsigned short ushort_t;
typedef unsigned int   uint_t;

typedef const __attribute__((address_space(1))) void as1_cvoid;
typedef __attribute__((address_space(3))) void as3_void;

__device__ __forceinline__ float sigmoidf_(float x) { return 1.f / (1.f + __expf(-x)); }
__device__ __forceinline__ float tanh_fast(float x) { return 2.f / (1.f + __expf(-2.f * x)) - 1.f; }
__device__ __forceinline__ ushort_t f2bf(float f) {
    unsigned int u = __float_as_uint(f);
    u += 0x7FFFu + ((u >> 16) & 1u);
    return (ushort_t)(u >> 16);
}

__global__ __launch_bounds__(256) void fill_zero_kernel(uint_t* __restrict__ p, int n) {
    int i = blockIdx.x * 256 + threadIdx.x;
    if (i < n) p[i] = 0u;
}

// Wfrag[br][tap][kk][wm][mf][lane][e]: m = wm*64 + gate*16 + ocl, gate=mf, oc=wm*16+l16.
__global__ __launch_bounds__(256) void repack_w_kernel(
    const float* __restrict__ w1, const float* __restrict__ w2, ushort_t* __restrict__ Wfrag)
{
    int id = blockIdx.x * 256 + threadIdx.x;
    if (id >= WFRAG_TOT) return;
    int e    = id & 7;
    int lane = (id >> 3) & 63;
    int mf   = (id >> 9) & 3;
    int wm   = (id >> 11) & 3;
    int rest = id >> 13;
    int kk   = rest % 3;
    int tap  = (rest / 3) % 9;
    int br   = rest / 27;
    int l16 = lane & 15, kh = lane >> 4;
    int gate = mf;
    int oc   = wm * 16 + l16;
    int k    = kh * 8 + e;
    int c;
    if (kk == 0)      c = (k < IND_) ? k : -1;
    else if (kk == 1) c = IND_ + k;
    else              c = IND_ + 32 + k;
    const float* w = br ? w2 : w1;
    float v = (c >= 0) ? w[((size_t)(gate * 64 + oc) * 89 + c) * 9 + tap] : 0.f;
    Wfrag[id] = f2bf(v);
}

__global__ __launch_bounds__(256) void repack_wc_kernel(
    const float* __restrict__ wc, ushort_t* __restrict__ Wc)
{
    int id = blockIdx.x * 256 + threadIdx.x;
    if (id >= 9 * 64 * 128) return;
    int k   = id % 128;
    int oc  = (id / 128) % 64;
    int tap = id / (128 * 64);
    Wc[id] = f2bf(wc[((size_t)(oc * 128) + k) * 9 + tap]);
}

// Standalone LN (only for t = 0; writes parity-0 x-bufs).
__global__ __launch_bounds__(256) void ln_t_kernel(
    const float* __restrict__ x, const float* __restrict__ gamma, const float* __restrict__ beta,
    ushort_t* __restrict__ xb0, ushort_t* __restrict__ xb1, int t)
{
    int p = blockIdx.x * 256 + threadIdx.x;
    if (p >= B_ * NPIX) return;
    int b = p / NPIX, hw = p % NPIX;
    int y = hw / 25, xx = hw % 25;
    const float* xp = x + ((size_t)(b * T_ + t) * IND_) * NPIX + hw;
    float v[IND_];
    float s = 0.f;
#pragma unroll
    for (int c = 0; c < IND_; ++c) { v[c] = xp[c * NPIX]; s += v[c]; }
    float mu = s * (1.f / IND_);
    float ss = 0.f;
#pragma unroll
    for (int c = 0; c < IND_; ++c) { float d = v[c] - mu; ss += d * d; }
    float rstd = rsqrtf(ss * (1.f / IND_) + 1e-5f);
    ushort_t* o0 = xb0 + (size_t)b * XB0 + (size_t)((y + 1) * WP0 + (xx + 1)) * XSTR;
    ushort_t* o1 = xb1 + (size_t)b * XB1 + (size_t)((y + 2) * WP1 + (xx + 2)) * XSTR;
#pragma unroll
    for (int c = 0; c < IND_; ++c) {
        ushort_t hv = f2bf((v[c] - mu) * rstd * gamma[c] + beta[c]);
        o0[c] = hv;
        o1[c] = hv;
    }
}

// One ConvLSTM timestep, both branches. h-tile AND x-tile async-staged into LDS;
// LN for step t+1 fused (63 threads/block, overlapped with stage drain);
// c in coalesced f32x4 layout.
__global__ __launch_bounds__(512) void convlstm_mfma_kernel(
    const float* __restrict__ x, const float* __restrict__ ln_g, const float* __restrict__ ln_b,
    ushort_t* __restrict__ xb0g, ushort_t* __restrict__ xb1g,
    const ushort_t* __restrict__ h0c, const ushort_t* __restrict__ h1c,
    ushort_t* __restrict__ h0n, ushort_t* __restrict__ h1n,
    const ushort_t* __restrict__ Wfrag,
    const float* __restrict__ bias1, const float* __restrict__ bias2,
    float* __restrict__ cst, int t)
{
    const int rg = blockIdx.x;
    const int b  = blockIdx.y;
    const int br = blockIdx.z;
    const int d  = 1 + br;
    const int Wp = 25 + 2 * d;
    const int par = t & 1, nxt = par ^ 1;
    const ushort_t* __restrict__ hc = (br ? h1c + (size_t)b * HB1 : h0c + (size_t)b * HB0);
    ushort_t* __restrict__ hn       = (br ? h1n + (size_t)b * HB1 : h0n + (size_t)b * HB0);
    const ushort_t* __restrict__ xbcur =
        br ? (xb1g + (size_t)par * XB1T + (size_t)b * XB1)
           : (xb0g + (size_t)par * XB0T + (size_t)b * XB0);
    const float* __restrict__ bias = br ? bias2 : bias1;
    const ushort_t* __restrict__ WFb = Wfrag + (size_t)br * WFRAG_PER_BR;
    // c layout: [(br*B+b)][ocq=16][pix] of f32x4
    f32x4* __restrict__ cb4 = (f32x4*)cst + (size_t)(br * B_ + b) * 16 * NPIX;

    __shared__ ushort_t tile[RST1 * HSTR];    // 39,168 B
    __shared__ ushort_t xtile[RST1 * XSTR];   // 17,408 B

    const int tid = threadIdx.x;
    const int u0  = rg * 5 * Wp;
    const int CH  = br ? CH1 : CH0;
    const int XCH = br ? XCH1 : XCH0;
    const int wave_u = tid & 448;

    // ---- async stage h-tile (linear 16B chunks)
    {
        const char* gsrc = (const char*)(hc + (size_t)u0 * HSTR);
#pragma unroll
        for (int j = 0; j < 5; ++j) {
            const int i = j * 512 + tid;
            if (i < CH) {
                __builtin_amdgcn_global_load_lds(
                    (as1_cvoid*)(gsrc + (size_t)i * 16),
                    (as3_void*)((char*)tile + (size_t)(j * 512 + wave_u) * 16),
                    16, 0, 0);
            }
        }
    }
    // ---- async stage x-tile (linear 16B chunks)
    {
        const char* gsrc = (const char*)(xbcur + (size_t)u0 * XSTR);
#pragma unroll
        for (int j = 0; j < 3; ++j) {
            const int i = j * 512 + tid;
            if (i < XCH) {
                __builtin_amdgcn_global_load_lds(
                    (as1_cvoid*)(gsrc + (size_t)i * 16),
                    (as3_void*)((char*)xtile + (size_t)(j * 512 + wave_u) * 16),
                    16, 0, 0);
            }
        }
    }
    // ---- fused LN for step t+1 (writes opposite-parity x-bufs; overlaps stage drain)
    if (t + 1 < T_ && tid < 63) {
        const int linbid = (br * B_ + b) * 5 + rg;
        const int p = linbid * 63 + tid;
        if (p < B_ * NPIX) {
            const int bb = p / NPIX, hw = p - bb * NPIX;
            const int y = hw / 25, xx = hw - y * 25;
            const float* xp = x + ((size_t)(bb * T_ + t + 1) * IND_) * NPIX + hw;
            float v[IND_];
            float s = 0.f;
#pragma unroll
            for (int c = 0; c < IND_; ++c) { v[c] = xp[c * NPIX]; s += v[c]; }
            const float mu = s * (1.f / IND_);
            float ss = 0.f;
#pragma unroll
            for (int c = 0; c < IND_; ++c) { float dd = v[c] - mu; ss += dd * dd; }
            const float rstd = rsqrtf(ss * (1.f / IND_) + 1e-5f);
            ushort_t us[IND_];
#pragma unroll
            for (int c = 0; c < IND_; ++c) us[c] = f2bf((v[c] - mu) * rstd * ln_g[c] + ln_b[c]);
            uint4 q0, q1, q2;
            q0.x = us[0] | ((uint_t)us[1] << 16);   q0.y = us[2] | ((uint_t)us[3] << 16);
            q0.z = us[4] | ((uint_t)us[5] << 16);   q0.w = us[6] | ((uint_t)us[7] << 16);
            q1.x = us[8] | ((uint_t)us[9] << 16);   q1.y = us[10] | ((uint_t)us[11] << 16);
            q1.z = us[12] | ((uint_t)us[13] << 16); q1.w = us[14] | ((uint_t)us[15] << 16);
            q2.x = us[16] | ((uint_t)us[17] << 16); q2.y = us[18] | ((uint_t)us[19] << 16);
            q2.z = us[20] | ((uint_t)us[21] << 16); q2.w = us[22] | ((uint_t)us[23] << 16);
            ushort_t* o0 = xb0g + (size_t)nxt * XB0T + (size_t)bb * XB0
                           + (size_t)((y + 1) * WP0 + (xx + 1)) * XSTR;
            ushort_t* o1 = xb1g + (size_t)nxt * XB1T + (size_t)bb * XB1
                           + (size_t)((y + 2) * WP1 + (xx + 2)) * XSTR;
            *(uint4*)o0 = q0; *(uint4*)(o0 + 8) = q1; *(uint4*)(o0 + 16) = q2; o0[24] = us[24];
            *(uint4*)o1 = q0; *(uint4*)(o1 + 8) = q1; *(uint4*)(o1 + 16) = q2; o1[24] = us[24];
        }
    }
    __syncthreads();

    const int w    = tid >> 6, lane = tid & 63;
    const int wm   = w & 3, wn = w >> 2;
    const int l16  = lane & 15, kh = lane >> 4;
    const int koff = kh * 8;

    f32x4 acc[4][5];
#pragma unroll
    for (int i = 0; i < 4; ++i)
#pragma unroll
        for (int j = 0; j < 5; ++j) acc[i][j] = (f32x4){0.f, 0.f, 0.f, 0.f};

    int baserel[5];
#pragma unroll
    for (int nf = 0; nf < 5; ++nf) {
        int n = wn * 80 + nf * 16 + l16;
        baserel[nf] = (n >> 5) * Wp + (n & 31);
    }

    for (int tap = 0; tap < 9; ++tap) {
        const int ky = tap / 3, kx = tap - 3 * ky;
        const int toff = (ky * Wp + kx) * d;
        const ushort_t* __restrict__ WT = WFb + (size_t)(tap * 3) * 8192 + wm * 2048 + lane * 8;
        // kk=0: x from LDS x-tile
        {
            bf16x8 af[4], bfr[5];
#pragma unroll
            for (int mf = 0; mf < 4; ++mf)
                af[mf] = *(const bf16x8*)(WT + mf * 512);
#pragma unroll
            for (int nf = 0; nf < 5; ++nf)
                bfr[nf] = *(const bf16x8*)(xtile + (size_t)(baserel[nf] + toff) * XSTR + koff);
#pragma unroll
            for (int mf = 0; mf < 4; ++mf)
#pragma unroll
                for (int nf = 0; nf < 5; ++nf)
                    acc[mf][nf] = __builtin_amdgcn_mfma_f32_16x16x32_bf16(
                        af[mf], bfr[nf], acc[mf][nf], 0, 0, 0);
        }
        // kk=1,2: h from LDS h-tile
#pragma unroll
        for (int kkh = 0; kkh < 2; ++kkh) {
            bf16x8 af[4], bfr[5];
#pragma unroll
            for (int mf = 0; mf < 4; ++mf)
                af[mf] = *(const bf16x8*)(WT + (size_t)(kkh + 1) * 8192 + mf * 512);
#pragma unroll
            for (int nf = 0; nf < 5; ++nf)
                bfr[nf] = *(const bf16x8*)(tile + (baserel[nf] + toff) * HSTR + kkh * 32 + koff);
#pragma unroll
            for (int mf = 0; mf < 4; ++mf)
#pragma unroll
                for (int nf = 0; nf < 5; ++nf)
                    acc[mf][nf] = __builtin_amdgcn_mfma_f32_16x16x32_bf16(
                        af[mf], bfr[nf], acc[mf][nf], 0, 0, 0);
        }
    }

    // Epilogue: gates are mf (0..3); C/D reg r -> oc = wm*16 + kh*4 + r.
    const int oc0 = wm * 16 + kh * 4;
    const int ocq = wm * 4 + kh;
    float bi4[4], bf4[4], bo4[4], bg4[4];
#pragma unroll
    for (int r = 0; r < 4; ++r) {
        bi4[r] = bias[oc0 + r];
        bf4[r] = bias[64 + oc0 + r];
        bo4[r] = bias[128 + oc0 + r];
        bg4[r] = bias[192 + oc0 + r];
    }
#pragma unroll
    for (int nf = 0; nf < 5; ++nf) {
        const int n = wn * 80 + nf * 16 + l16;
        const int xx = n & 31;
        if (xx >= 25) continue;
        const int y = rg * 5 + (n >> 5);
        const int pix = y * 25 + xx;
        f32x4* cp = cb4 + (size_t)ocq * NPIX + pix;
        f32x4 cv;
        if (t != 0) cv = *cp;
        else        cv = (f32x4){0.f, 0.f, 0.f, 0.f};
        ushort_t hs[4];
#pragma unroll
        for (int r = 0; r < 4; ++r) {
            const float zi = acc[0][nf][r] + bi4[r];
            const float zf = acc[1][nf][r] + bf4[r];
            const float zo = acc[2][nf][r] + bo4[r];
            const float zg = acc[3][nf][r] + bg4[r];
            const float cn = sigmoidf_(zf) * cv[r] + sigmoidf_(zi) * tanh_fast(zg);
            cv[r] = cn;
            hs[r] = f2bf(sigmoidf_(zo) * tanh_fast(cn));
        }
        *cp = cv;
        uint2 hv;
        hv.x = (uint_t)hs[0] | ((uint_t)hs[1] << 16);
        hv.y = (uint_t)hs[2] | ((uint_t)hs[3] << 16);
        *(uint2*)(hn + (size_t)((y + d) * Wp + (xx + d)) * HSTR + oc0) = hv;
    }
}

// Combine final hidden states into Hc[b][(y+1)*27+(x+1)][k=128] bf16.
__global__ __launch_bounds__(256) void combine_h_kernel(
    const ushort_t* __restrict__ h0, const ushort_t* __restrict__ h1, ushort_t* __restrict__ Hc)
{
    int id = blockIdx.x * 256 + threadIdx.x;
    if (id >= B_ * NPIX * 128) return;
    int k   = id % 128;
    int pix = (id / 128) % NPIX;
    int b   = id / (128 * NPIX);
    int y = pix / 25, xx = pix % 25;
    ushort_t v;
    if (k < 64) v = h0[(size_t)b * HB0 + (size_t)((y + 1) * WP0 + (xx + 1)) * HSTR + k];
    else        v = h1[(size_t)b * HB1 + (size_t)((y + 2) * WP1 + (xx + 2)) * HSTR + (k - 64)];
    Hc[(size_t)b * HCB + (size_t)((y + 1) * 27 + (xx + 1)) * 128 + k] = v;
}

// Final 3x3 conv (128->64, pad 1) + bias + ReLU via MFMA implicit-GEMM.
__global__ __launch_bounds__(512) void conv_mfma_kernel(
    const ushort_t* __restrict__ Hc, const ushort_t* __restrict__ Wc,
    const float* __restrict__ bc, float* __restrict__ conv_out)
{
    const int rg = blockIdx.x;
    const int b  = blockIdx.y;
    const ushort_t* __restrict__ Hb = Hc + (size_t)b * HCB;

    const int tid  = threadIdx.x;
    const int w    = tid >> 6, lane = tid & 63;
    const int wm   = w & 1, wn = w >> 1;
    const int l16  = lane & 15, kh = lane >> 4;
    const int koff = kh * 8;

    f32x4 acc[2][2];
#pragma unroll
    for (int i = 0; i < 2; ++i)
#pragma unroll
        for (int j = 0; j < 2; ++j) acc[i][j] = (f32x4){0.f, 0.f, 0.f, 0.f};

    int baserow[2];
#pragma unroll
    for (int nf = 0; nf < 2; ++nf) {
        int n = wn * 32 + nf * 16 + l16;
        baserow[nf] = (rg * 4 + (n >> 5)) * 27 + (n & 31);
    }
    const ushort_t* __restrict__ Wm = Wc + (size_t)(wm * 32 + l16) * 128 + koff;

    for (int tap = 0; tap < 9; ++tap) {
        const int ky = tap / 3, kx = tap - 3 * ky;
        const int toff = ky * 27 + kx;
        const ushort_t* __restrict__ Wt = Wm + (size_t)tap * (64 * 128);
        const ushort_t* Urow[2];
#pragma unroll
        for (int nf = 0; nf < 2; ++nf)
            Urow[nf] = Hb + (size_t)(baserow[nf] + toff) * 128 + koff;
#pragma unroll
        for (int kk = 0; kk < 4; ++kk) {
            bf16x8 af[2], bfr[2];
#pragma unroll
            for (int mf = 0; mf < 2; ++mf)
                af[mf] = *(const bf16x8*)(Wt + mf * 16 * 128 + kk * 32);
#pragma unroll
            for (int nf = 0; nf < 2; ++nf)
                bfr[nf] = *(const bf16x8*)(Urow[nf] + kk * 32);
#pragma unroll
            for (int mf = 0; mf < 2; ++mf)
#pragma unroll
                for (int nf = 0; nf < 2; ++nf)
                    acc[mf][nf] = __builtin_amdgcn_mfma_f32_16x16x32_bf16(
                        af[mf], bfr[nf], acc[mf][nf], 0, 0, 0);
        }
    }

#pragma unroll
    for (int mf = 0; mf < 2; ++mf) {
#pragma unroll
        for (int nf = 0; nf < 2; ++nf) {
            const int n = wn * 32 + nf * 16 + l16;
            const int xx = n & 31;
            if (xx >= 25) continue;
            const int y = rg * 4 + wn;
            if (y >= 25) continue;
#pragma unroll
            for (int r = 0; r < 4; ++r) {
                const int oc = wm * 32 + mf * 16 + kh * 4 + r;
                const float v = fmaxf(acc[mf][nf][r] + bc[oc], 0.f);
                conv_out[((size_t)(b * 64 + oc)) * NPIX + y * 25 + xx] = v;
            }
        }
    }
}

__global__ __launch_bounds__(256) void pool_kernel(
    const float* __restrict__ conv_out, float* __restrict__ pool)
{
    int id = blockIdx.x * 256 + threadIdx.x;
    if (id >= B_ * 64 * 144) return;
    int px = id % 12;
    int py = (id / 12) % 12;
    int oc = (id / 144) % 64;
    int b  = id / (144 * 64);
    const float* p = conv_out + ((size_t)(b * 64 + oc)) * NPIX;
    const int cy = 2 * py, cx = 2 * px;
    float mx = fmaxf(fmaxf(p[cy * 25 + cx], p[cy * 25 + cx + 1]),
                     fmaxf(p[(cy + 1) * 25 + cx], p[(cy + 1) * 25 + cx + 1]));
    pool[(size_t)b * 9216 + oc * 144 + py * 12 + px] = mx;
}

__global__ __launch_bounds__(256) void fc1_kernel(
    const float* __restrict__ pool, const float* __restrict__ w1, const float* __restrict__ b1,
    float* __restrict__ f1)
{
    const int task = blockIdx.x * 4 + (threadIdx.x >> 6);
    const int lane = threadIdx.x & 63;
    const int b = task >> 6, oc = task & 63;
    const float* pr = pool + (size_t)b * 9216;
    const float* wr = w1 + (size_t)oc * 9216;
    float acc = 0.f;
#pragma unroll 4
    for (int it = 0; it < 36; ++it) {
        const int k = it * 256 + lane * 4;
        const float4 p = *(const float4*)(pr + k);
        const float4 ww = *(const float4*)(wr + k);
        acc += p.x * ww.x + p.y * ww.y + p.z * ww.z + p.w * ww.w;
    }
#pragma unroll
    for (int off = 32; off > 0; off >>= 1) acc += __shfl_down(acc, off);
    if (lane == 0) f1[b * 64 + oc] = fmaxf(acc + b1[oc], 0.f);
}

__global__ __launch_bounds__(64) void head2_kernel(
    const float* __restrict__ f1,
    const float* __restrict__ w2, const float* __restrict__ b2,
    const float* __restrict__ w3, const float* __restrict__ b3,
    float* __restrict__ out)
{
    const int b = blockIdx.x;
    __shared__ float f1l[64];
    __shared__ float f2[32];
    const int tid = threadIdx.x;
    f1l[tid] = f1[b * 64 + tid];
    __syncthreads();
    if (tid < 32) {
        float acc = b2[tid];
        const float* wr = w2 + (size_t)tid * 64;
#pragma unroll
        for (int k = 0; k < 64; ++k) acc += f1l[k] * wr[k];
        f2[tid] = fmaxf(acc, 0.f);
    }
    __syncthreads();
    if (tid == 0) {
        float y0 = b3[0], y1 = b3[1];
#pragma unroll
        for (int k = 0; k < 32; ++k) { y0 += f2[k] * w3[k]; y1 += f2[k] * w3[32 + k]; }
        const float m = fmaxf(y0, y1);
        const float lse = m + logf(expf(y0 - m) + expf(y1 - m));
        out[b * 2 + 0] = y0 - lse;
        out[b * 2 + 1] = y1 - lse;
    }
}

extern "C" void kernel_launch(void* const* d_in, const int* in_sizes, int n_in,
                              void* d_out, int out_size, void* d_ws, size_t ws_size,
                              hipStream_t stream) {
    const float* x    = (const float*)d_in[0];
    const float* ln_g = (const float*)d_in[1];
    const float* ln_b = (const float*)d_in[2];
    const float* w_l1 = (const float*)d_in[3];
    const float* b_l1 = (const float*)d_in[4];
    const float* w_l2 = (const float*)d_in[5];
    const float* b_l2 = (const float*)d_in[6];
    const float* w_c  = (const float*)d_in[7];
    const float* b_c  = (const float*)d_in[8];
    const float* w_f1 = (const float*)d_in[9];
    const float* b_f1 = (const float*)d_in[10];
    const float* w_f2 = (const float*)d_in[11];
    const float* b_f2 = (const float*)d_in[12];
    const float* w_f3 = (const float*)d_in[13];
    const float* b_f3 = (const float*)d_in[14];

    // Workspace (ushort offsets):
    //   xb0 (2 parities) @0: 3,047,424 | xb1 (2 par): 3,506,176
    //   h0A | h1A | h0B | h1B: 14,745,600
    //   cst fp32 (5,120,000 f, coalesced f32x4): 10,240,000 ush-equiv
    //   Wfrag 442,368 | Wc 73,728 | f1 8,192   -> total 32,063,488 ush = 64.1 MB
    //   tail aliases: Hc -> h0B/h1B (dead); conv_out+pool -> cst (dead).
    ushort_t* wsu = (ushort_t*)d_ws;
    uint_t*   wsi = (uint_t*)d_ws;

    ushort_t* xb0 = wsu;                          // 2 * XB0T
    ushort_t* xb1 = xb0 + 2 * (size_t)XB0T;       // 2 * XB1T
    ushort_t* h0A = xb1 + 2 * (size_t)XB1T;
    ushort_t* h1A = h0A + HB0T;
    ushort_t* h0B = h1A + HB1T;
    ushort_t* h1B = h0B + HB0T;
    float*    cst = (float*)(h1B + HB1T);
    float*    conv_out = cst;
    float*    pool = cst + 2560000;
    ushort_t* Wfrag = (ushort_t*)cst + 10240000;
    ushort_t* Wc    = Wfrag + WFRAG_TOT;
    float*    f1    = (float*)(Wc + 73728);
    ushort_t* Hc    = h0B;

    // zero x-bufs (both parities, borders) + h-bufs (borders + h0 state)
    const size_t zt = 2 * (size_t)XB0T + 2 * (size_t)XB1T + 2 * (size_t)HPART;
    fill_zero_kernel<<<((int)(zt / 2) + 255) / 256, 256, 0, stream>>>(wsi, (int)(zt / 2));
    repack_w_kernel<<<(WFRAG_TOT + 255) / 256, 256, 0, stream>>>(w_l1, w_l2, Wfrag);
    repack_wc_kernel<<<(9 * 64 * 128 + 255) / 256, 256, 0, stream>>>(w_c, Wc);

    // LN for t=0 into parity-0 x-bufs
    ln_t_kernel<<<(B_ * NPIX + 255) / 256, 256, 0, stream>>>(x, ln_g, ln_b, xb0, xb1, 0);

    ushort_t* H0[2] = {h0A, h0B};
    ushort_t* H1[2] = {h1A, h1B};
    for (int t = 0; t < T_; ++t) {
        const int cur = t & 1, nxt = cur ^ 1;
        convlstm_mfma_kernel<<<dim3(5, B_, 2), 512, 0, stream>>>(
            x, ln_g, ln_b, xb0, xb1,
            H0[cur], H1[cur], H0[nxt], H1[nxt], Wfrag, b_l1, b_l2, cst, t);
    }
    // final h in parity-0 (A). Hc overwrites dead B half: zero it first.
    fill_zero_kernel<<<(HCTOT / 2 + 255) / 256, 256, 0, stream>>>((uint_t*)Hc, HCTOT / 2);
    combine_h_kernel<<<(B_ * NPIX * 128 + 255) / 256, 256, 0, stream>>>(h0A, h1A, Hc);
    conv_mfma_kernel<<<dim3(7, B_), 512, 0, stream>>>(Hc, Wc, b_c, conv_out);
    pool_kernel<<<(B_ * 64 * 144 + 255) / 256, 256, 0, stream>>>(conv_out, pool);
    fc1_kernel<<<1024, 256, 0, stream>>>(pool, w_f1, b_f1, f1);
    head2_kernel<<<B_, 64, 0, stream>>>(f1, w_f2, b_f2, w_f3, b_f3, (float*)d_out);
}

// Round 11
// 1920.807 us; speedup vs baseline: 2.4601x; 1.0313x over previous
//
#include <hip/hip_runtime.h>
#include <hip/hip_bf16.h>
#include <math.h>

#define B_    64
#define T_    24
#define IND_  25
#define HID_  64
#define NPIX  625

// padded-grid geometry
#define WP0   27
#define WP1   29
#define XSTR  32          // x-buf pixel stride (ushorts)
#define HSTR  72          // h-buf pixel stride (ushorts)
#define XROWS0 800
#define XROWS1 912
#define HROWS0 800
#define HROWS1 912
#define XB0   (XROWS0*XSTR)   // 25,600
#define XB1   (XROWS1*XSTR)   // 29,184
#define HB0   (HROWS0*HSTR)   // 57,600
#define HB1   (HROWS1*HSTR)   // 65,664
#define XB0T  (B_*XB0)        // 1,638,400 per parity
#define XB1T  (B_*XB1)        // 1,867,776
#define HB0T  (B_*HB0)        // 3,686,400
#define HB1T  (B_*HB1)        // 4,202,496
#define HPART (HB0T+HB1T)     // 7,888,896 per parity

// 3-row rowgroups: staged rows / 16B chunks per branch
#define NRG   9
#define RST0  144
#define RST1  212
#define CH0   (RST0*9)    // 1296  h chunks
#define CH1   (RST1*9)    // 1908
#define XCH0  (RST0*4)    // 576   x chunks
#define XCH1  (RST1*4)    // 848

// final-conv combined input: [b][832 rows][128] bf16
#define HCROWS 832
#define HCB    (HCROWS*128)
#define HCTOT  (B_*HCB)

#define WFRAG_PER_BR (9*3*4*4*512)    // 221,184
#define WFRAG_TOT    (2*WFRAG_PER_BR)

typedef __bf16 bf16x8 __attribute__((ext_vector_type(8)));
typedef float  f32x4  __attribute__((ext_vector_type(4)));
typedef unsigned short ushort_t;
typedef unsigned int   uint_t;

typedef const __attribute__((address_space(1))) void as1_cvoid;
typedef __attribute__((address_space(3))) void as3_void;

__device__ __forceinline__ float sigmoidf_(float x) { return 1.f / (1.f + __expf(-x)); }
__device__ __forceinline__ float tanh_fast(float x) { return 2.f / (1.f + __expf(-2.f * x)) - 1.f; }
__device__ __forceinline__ ushort_t f2bf(float f) {
    unsigned int u = __float_as_uint(f);
    u += 0x7FFFu + ((u >> 16) & 1u);
    return (ushort_t)(u >> 16);
}

__global__ __launch_bounds__(256) void fill_zero_kernel(uint_t* __restrict__ p, int n) {
    int i = blockIdx.x * 256 + threadIdx.x;
    if (i < n) p[i] = 0u;
}

// Wfrag[br][tap][kk][wm][mf][lane][e]: m = wm*64 + gate*16 + ocl, gate=mf, oc=wm*16+l16.
__global__ __launch_bounds__(256) void repack_w_kernel(
    const float* __restrict__ w1, const float* __restrict__ w2, ushort_t* __restrict__ Wfrag)
{
    int id = blockIdx.x * 256 + threadIdx.x;
    if (id >= WFRAG_TOT) return;
    int e    = id & 7;
    int lane = (id >> 3) & 63;
    int mf   = (id >> 9) & 3;
    int wm   = (id >> 11) & 3;
    int rest = id >> 13;
    int kk   = rest % 3;
    int tap  = (rest / 3) % 9;
    int br   = rest / 27;
    int l16 = lane & 15, kh = lane >> 4;
    int gate = mf;
    int oc   = wm * 16 + l16;
    int k    = kh * 8 + e;
    int c;
    if (kk == 0)      c = (k < IND_) ? k : -1;
    else if (kk == 1) c = IND_ + k;
    else              c = IND_ + 32 + k;
    const float* w = br ? w2 : w1;
    float v = (c >= 0) ? w[((size_t)(gate * 64 + oc) * 89 + c) * 9 + tap] : 0.f;
    Wfrag[id] = f2bf(v);
}

__global__ __launch_bounds__(256) void repack_wc_kernel(
    const float* __restrict__ wc, ushort_t* __restrict__ Wc)
{
    int id = blockIdx.x * 256 + threadIdx.x;
    if (id >= 9 * 64 * 128) return;
    int k   = id % 128;
    int oc  = (id / 128) % 64;
    int tap = id / (128 * 64);
    Wc[id] = f2bf(wc[((size_t)(oc * 128) + k) * 9 + tap]);
}

// Standalone LN (only for t = 0; writes parity-0 x-bufs).
__global__ __launch_bounds__(256) void ln_t_kernel(
    const float* __restrict__ x, const float* __restrict__ gamma, const float* __restrict__ beta,
    ushort_t* __restrict__ xb0, ushort_t* __restrict__ xb1, int t)
{
    int p = blockIdx.x * 256 + threadIdx.x;
    if (p >= B_ * NPIX) return;
    int b = p / NPIX, hw = p % NPIX;
    int y = hw / 25, xx = hw % 25;
    const float* xp = x + ((size_t)(b * T_ + t) * IND_) * NPIX + hw;
    float v[IND_];
    float s = 0.f;
#pragma unroll
    for (int c = 0; c < IND_; ++c) { v[c] = xp[c * NPIX]; s += v[c]; }
    float mu = s * (1.f / IND_);
    float ss = 0.f;
#pragma unroll
    for (int c = 0; c < IND_; ++c) { float d = v[c] - mu; ss += d * d; }
    float rstd = rsqrtf(ss * (1.f / IND_) + 1e-5f);
    ushort_t* o0 = xb0 + (size_t)b * XB0 + (size_t)((y + 1) * WP0 + (xx + 1)) * XSTR;
    ushort_t* o1 = xb1 + (size_t)b * XB1 + (size_t)((y + 2) * WP1 + (xx + 2)) * XSTR;
#pragma unroll
    for (int c = 0; c < IND_; ++c) {
        ushort_t hv = f2bf((v[c] - mu) * rstd * gamma[c] + beta[c]);
        o0[c] = hv;
        o1[c] = hv;
    }
}

// One ConvLSTM timestep, both branches. 3-row rowgroups (NF=3 -> 48-AGPR acc),
// h+x tiles async-staged into LDS; fused LN(t+1); c in coalesced f32x4 layout.
// launch_bounds(512,4): cap 128 regs total -> 2 blocks/CU.
__global__ __launch_bounds__(512, 4) void convlstm_mfma_kernel(
    const float* __restrict__ x, const float* __restrict__ ln_g, const float* __restrict__ ln_b,
    ushort_t* __restrict__ xb0g, ushort_t* __restrict__ xb1g,
    const ushort_t* __restrict__ h0c, const ushort_t* __restrict__ h1c,
    ushort_t* __restrict__ h0n, ushort_t* __restrict__ h1n,
    const ushort_t* __restrict__ Wfrag,
    const float* __restrict__ bias1, const float* __restrict__ bias2,
    float* __restrict__ cst, int t)
{
    const int rg = blockIdx.x;
    const int b  = blockIdx.y;
    const int br = blockIdx.z;
    const int d  = 1 + br;
    const int Wp = 25 + 2 * d;
    const int par = t & 1, nxt = par ^ 1;
    const ushort_t* __restrict__ hc = (br ? h1c + (size_t)b * HB1 : h0c + (size_t)b * HB0);
    ushort_t* __restrict__ hn       = (br ? h1n + (size_t)b * HB1 : h0n + (size_t)b * HB0);
    const ushort_t* __restrict__ xbcur =
        br ? (xb1g + (size_t)par * XB1T + (size_t)b * XB1)
           : (xb0g + (size_t)par * XB0T + (size_t)b * XB0);
    const float* __restrict__ bias = br ? bias2 : bias1;
    const ushort_t* __restrict__ WFb = Wfrag + (size_t)br * WFRAG_PER_BR;
    // c layout: [(br*B+b)][ocq=16][pix] of f32x4
    f32x4* __restrict__ cb4 = (f32x4*)cst + (size_t)(br * B_ + b) * 16 * NPIX;

    __shared__ ushort_t tile[RST1 * HSTR];    // 30,528 B
    __shared__ ushort_t xtile[RST1 * XSTR];   // 13,568 B

    const int tid = threadIdx.x;
    const int u0  = rg * 3 * Wp;
    const int CH  = br ? CH1 : CH0;
    const int XCH = br ? XCH1 : XCH0;
    const int wave_u = tid & 448;

    // ---- async stage h-tile (linear 16B chunks)
    {
        const char* gsrc = (const char*)(hc + (size_t)u0 * HSTR);
#pragma unroll
        for (int j = 0; j < 4; ++j) {
            const int i = j * 512 + tid;
            if (i < CH) {
                __builtin_amdgcn_global_load_lds(
                    (as1_cvoid*)(gsrc + (size_t)i * 16),
                    (as3_void*)((char*)tile + (size_t)(j * 512 + wave_u) * 16),
                    16, 0, 0);
            }
        }
    }
    // ---- async stage x-tile (linear 16B chunks)
    {
        const char* gsrc = (const char*)(xbcur + (size_t)u0 * XSTR);
#pragma unroll
        for (int j = 0; j < 2; ++j) {
            const int i = j * 512 + tid;
            if (i < XCH) {
                __builtin_amdgcn_global_load_lds(
                    (as1_cvoid*)(gsrc + (size_t)i * 16),
                    (as3_void*)((char*)xtile + (size_t)(j * 512 + wave_u) * 16),
                    16, 0, 0);
            }
        }
    }
    // ---- fused LN for step t+1 (writes opposite-parity x-bufs; overlaps stage drain)
    if (t + 1 < T_ && tid < 35) {
        const int linbid = (br * B_ + b) * NRG + rg;
        const int p = linbid * 35 + tid;
        if (p < B_ * NPIX) {
            const int bb = p / NPIX, hw = p - bb * NPIX;
            const int y = hw / 25, xx = hw - y * 25;
            const float* xp = x + ((size_t)(bb * T_ + t + 1) * IND_) * NPIX + hw;
            float v[IND_];
            float s = 0.f;
#pragma unroll
            for (int c = 0; c < IND_; ++c) { v[c] = xp[c * NPIX]; s += v[c]; }
            const float mu = s * (1.f / IND_);
            float ss = 0.f;
#pragma unroll
            for (int c = 0; c < IND_; ++c) { float dd = v[c] - mu; ss += dd * dd; }
            const float rstd = rsqrtf(ss * (1.f / IND_) + 1e-5f);
            ushort_t us[IND_];
#pragma unroll
            for (int c = 0; c < IND_; ++c) us[c] = f2bf((v[c] - mu) * rstd * ln_g[c] + ln_b[c]);
            uint4 q0, q1, q2;
            q0.x = us[0] | ((uint_t)us[1] << 16);   q0.y = us[2] | ((uint_t)us[3] << 16);
            q0.z = us[4] | ((uint_t)us[5] << 16);   q0.w = us[6] | ((uint_t)us[7] << 16);
            q1.x = us[8] | ((uint_t)us[9] << 16);   q1.y = us[10] | ((uint_t)us[11] << 16);
            q1.z = us[12] | ((uint_t)us[13] << 16); q1.w = us[14] | ((uint_t)us[15] << 16);
            q2.x = us[16] | ((uint_t)us[17] << 16); q2.y = us[18] | ((uint_t)us[19] << 16);
            q2.z = us[20] | ((uint_t)us[21] << 16); q2.w = us[22] | ((uint_t)us[23] << 16);
            ushort_t* o0 = xb0g + (size_t)nxt * XB0T + (size_t)bb * XB0
                           + (size_t)((y + 1) * WP0 + (xx + 1)) * XSTR;
            ushort_t* o1 = xb1g + (size_t)nxt * XB1T + (size_t)bb * XB1
                           + (size_t)((y + 2) * WP1 + (xx + 2)) * XSTR;
            *(uint4*)o0 = q0; *(uint4*)(o0 + 8) = q1; *(uint4*)(o0 + 16) = q2; o0[24] = us[24];
            *(uint4*)o1 = q0; *(uint4*)(o1 + 8) = q1; *(uint4*)(o1 + 16) = q2; o1[24] = us[24];
        }
    }
    __syncthreads();

    const int w    = tid >> 6, lane = tid & 63;
    const int wm   = w & 3, wn = w >> 2;
    const int l16  = lane & 15, kh = lane >> 4;
    const int koff = kh * 8;

    f32x4 acc[4][3];
#pragma unroll
    for (int i = 0; i < 4; ++i)
#pragma unroll
        for (int j = 0; j < 3; ++j) acc[i][j] = (f32x4){0.f, 0.f, 0.f, 0.f};

    int baserel[3];
#pragma unroll
    for (int nf = 0; nf < 3; ++nf) {
        int n = wn * 48 + nf * 16 + l16;
        baserel[nf] = (n >> 5) * Wp + (n & 31);
    }

    for (int tap = 0; tap < 9; ++tap) {
        const int ky = tap / 3, kx = tap - 3 * ky;
        const int toff = (ky * Wp + kx) * d;
        const ushort_t* __restrict__ WT = WFb + (size_t)(tap * 3) * 8192 + wm * 2048 + lane * 8;
        // kk=0: x from LDS x-tile
        {
            bf16x8 af[4], bfr[3];
#pragma unroll
            for (int mf = 0; mf < 4; ++mf)
                af[mf] = *(const bf16x8*)(WT + mf * 512);
#pragma unroll
            for (int nf = 0; nf < 3; ++nf)
                bfr[nf] = *(const bf16x8*)(xtile + (size_t)(baserel[nf] + toff) * XSTR + koff);
#pragma unroll
            for (int mf = 0; mf < 4; ++mf)
#pragma unroll
                for (int nf = 0; nf < 3; ++nf)
                    acc[mf][nf] = __builtin_amdgcn_mfma_f32_16x16x32_bf16(
                        af[mf], bfr[nf], acc[mf][nf], 0, 0, 0);
        }
        // kk=1,2: h from LDS h-tile
#pragma unroll
        for (int kkh = 0; kkh < 2; ++kkh) {
            bf16x8 af[4], bfr[3];
#pragma unroll
            for (int mf = 0; mf < 4; ++mf)
                af[mf] = *(const bf16x8*)(WT + (size_t)(kkh + 1) * 8192 + mf * 512);
#pragma unroll
            for (int nf = 0; nf < 3; ++nf)
                bfr[nf] = *(const bf16x8*)(tile + (baserel[nf] + toff) * HSTR + kkh * 32 + koff);
#pragma unroll
            for (int mf = 0; mf < 4; ++mf)
#pragma unroll
                for (int nf = 0; nf < 3; ++nf)
                    acc[mf][nf] = __builtin_amdgcn_mfma_f32_16x16x32_bf16(
                        af[mf], bfr[nf], acc[mf][nf], 0, 0, 0);
        }
    }

    // Epilogue (bias loaded here, after the MFMA loop, to cut live regs in the hot loop).
    const int oc0 = wm * 16 + kh * 4;
    const int ocq = wm * 4 + kh;
    float bi4[4], bf4[4], bo4[4], bg4[4];
#pragma unroll
    for (int r = 0; r < 4; ++r) {
        bi4[r] = bias[oc0 + r];
        bf4[r] = bias[64 + oc0 + r];
        bo4[r] = bias[128 + oc0 + r];
        bg4[r] = bias[192 + oc0 + r];
    }
#pragma unroll
    for (int nf = 0; nf < 3; ++nf) {
        const int n = wn * 48 + nf * 16 + l16;
        const int xx = n & 31;
        if (xx >= 25) continue;
        const int y = rg * 3 + (n >> 5);
        if (y >= 25) continue;
        const int pix = y * 25 + xx;
        f32x4* cp = cb4 + (size_t)ocq * NPIX + pix;
        f32x4 cv;
        if (t != 0) cv = *cp;
        else        cv = (f32x4){0.f, 0.f, 0.f, 0.f};
        ushort_t hs[4];
#pragma unroll
        for (int r = 0; r < 4; ++r) {
            const float zi = acc[0][nf][r] + bi4[r];
            const float zf = acc[1][nf][r] + bf4[r];
            const float zo = acc[2][nf][r] + bo4[r];
            const float zg = acc[3][nf][r] + bg4[r];
            const float cn = sigmoidf_(zf) * cv[r] + sigmoidf_(zi) * tanh_fast(zg);
            cv[r] = cn;
            hs[r] = f2bf(sigmoidf_(zo) * tanh_fast(cn));
        }
        *cp = cv;
        uint2 hv;
        hv.x = (uint_t)hs[0] | ((uint_t)hs[1] << 16);
        hv.y = (uint_t)hs[2] | ((uint_t)hs[3] << 16);
        *(uint2*)(hn + (size_t)((y + d) * Wp + (xx + d)) * HSTR + oc0) = hv;
    }
}

// Combine final hidden states into Hc[b][(y+1)*27+(x+1)][k=128] bf16.
__global__ __launch_bounds__(256) void combine_h_kernel(
    const ushort_t* __restrict__ h0, const ushort_t* __restrict__ h1, ushort_t* __restrict__ Hc)
{
    int id = blockIdx.x * 256 + threadIdx.x;
    if (id >= B_ * NPIX * 128) return;
    int k   = id % 128;
    int pix = (id / 128) % NPIX;
    int b   = id / (128 * NPIX);
    int y = pix / 25, xx = pix % 25;
    ushort_t v;
    if (k < 64) v = h0[(size_t)b * HB0 + (size_t)((y + 1) * WP0 + (xx + 1)) * HSTR + k];
    else        v = h1[(size_t)b * HB1 + (size_t)((y + 2) * WP1 + (xx + 2)) * HSTR + (k - 64)];
    Hc[(size_t)b * HCB + (size_t)((y + 1) * 27 + (xx + 1)) * 128 + k] = v;
}

// Final 3x3 conv (128->64, pad 1) + bias + ReLU via MFMA implicit-GEMM.
__global__ __launch_bounds__(512) void conv_mfma_kernel(
    const ushort_t* __restrict__ Hc, const ushort_t* __restrict__ Wc,
    const float* __restrict__ bc, float* __restrict__ conv_out)
{
    const int rg = blockIdx.x;
    const int b  = blockIdx.y;
    const ushort_t* __restrict__ Hb = Hc + (size_t)b * HCB;

    const int tid  = threadIdx.x;
    const int w    = tid >> 6, lane = tid & 63;
    const int wm   = w & 1, wn = w >> 1;
    const int l16  = lane & 15, kh = lane >> 4;
    const int koff = kh * 8;

    f32x4 acc[2][2];
#pragma unroll
    for (int i = 0; i < 2; ++i)
#pragma unroll
        for (int j = 0; j < 2; ++j) acc[i][j] = (f32x4){0.f, 0.f, 0.f, 0.f};

    int baserow[2];
#pragma unroll
    for (int nf = 0; nf < 2; ++nf) {
        int n = wn * 32 + nf * 16 + l16;
        baserow[nf] = (rg * 4 + (n >> 5)) * 27 + (n & 31);
    }
    const ushort_t* __restrict__ Wm = Wc + (size_t)(wm * 32 + l16) * 128 + koff;

    for (int tap = 0; tap < 9; ++tap) {
        const int ky = tap / 3, kx = tap - 3 * ky;
        const int toff = ky * 27 + kx;
        const ushort_t* __restrict__ Wt = Wm + (size_t)tap * (64 * 128);
        const ushort_t* Urow[2];
#pragma unroll
        for (int nf = 0; nf < 2; ++nf)
            Urow[nf] = Hb + (size_t)(baserow[nf] + toff) * 128 + koff;
#pragma unroll
        for (int kk = 0; kk < 4; ++kk) {
            bf16x8 af[2], bfr[2];
#pragma unroll
            for (int mf = 0; mf < 2; ++mf)
                af[mf] = *(const bf16x8*)(Wt + mf * 16 * 128 + kk * 32);
#pragma unroll
            for (int nf = 0; nf < 2; ++nf)
                bfr[nf] = *(const bf16x8*)(Urow[nf] + kk * 32);
#pragma unroll
            for (int mf = 0; mf < 2; ++mf)
#pragma unroll
                for (int nf = 0; nf < 2; ++nf)
                    acc[mf][nf] = __builtin_amdgcn_mfma_f32_16x16x32_bf16(
                        af[mf], bfr[nf], acc[mf][nf], 0, 0, 0);
        }
    }

#pragma unroll
    for (int mf = 0; mf < 2; ++mf) {
#pragma unroll
        for (int nf = 0; nf < 2; ++nf) {
            const int n = wn * 32 + nf * 16 + l16;
            const int xx = n & 31;
            if (xx >= 25) continue;
            const int y = rg * 4 + wn;
            if (y >= 25) continue;
#pragma unroll
            for (int r = 0; r < 4; ++r) {
                const int oc = wm * 32 + mf * 16 + kh * 4 + r;
                const float v = fmaxf(acc[mf][nf][r] + bc[oc], 0.f);
                conv_out[((size_t)(b * 64 + oc)) * NPIX + y * 25 + xx] = v;
            }
        }
    }
}

__global__ __launch_bounds__(256) void pool_kernel(
    const float* __restrict__ conv_out, float* __restrict__ pool)
{
    int id = blockIdx.x * 256 + threadIdx.x;
    if (id >= B_ * 64 * 144) return;
    int px = id % 12;
    int py = (id / 12) % 12;
    int oc = (id / 144) % 64;
    int b  = id / (144 * 64);
    const float* p = conv_out + ((size_t)(b * 64 + oc)) * NPIX;
    const int cy = 2 * py, cx = 2 * px;
    float mx = fmaxf(fmaxf(p[cy * 25 + cx], p[cy * 25 + cx + 1]),
                     fmaxf(p[(cy + 1) * 25 + cx], p[(cy + 1) * 25 + cx + 1]));
    pool[(size_t)b * 9216 + oc * 144 + py * 12 + px] = mx;
}

__global__ __launch_bounds__(256) void fc1_kernel(
    const float* __restrict__ pool, const float* __restrict__ w1, const float* __restrict__ b1,
    float* __restrict__ f1)
{
    const int task = blockIdx.x * 4 + (threadIdx.x >> 6);
    const int lane = threadIdx.x & 63;
    const int b = task >> 6, oc = task & 63;
    const float* pr = pool + (size_t)b * 9216;
    const float* wr = w1 + (size_t)oc * 9216;
    float acc = 0.f;
#pragma unroll 4
    for (int it = 0; it < 36; ++it) {
        const int k = it * 256 + lane * 4;
        const float4 p = *(const float4*)(pr + k);
        const float4 ww = *(const float4*)(wr + k);
        acc += p.x * ww.x + p.y * ww.y + p.z * ww.z + p.w * ww.w;
    }
#pragma unroll
    for (int off = 32; off > 0; off >>= 1) acc += __shfl_down(acc, off);
    if (lane == 0) f1[b * 64 + oc] = fmaxf(acc + b1[oc], 0.f);
}

__global__ __launch_bounds__(64) void head2_kernel(
    const float* __restrict__ f1,
    const float* __restrict__ w2, const float* __restrict__ b2,
    const float* __restrict__ w3, const float* __restrict__ b3,
    float* __restrict__ out)
{
    const int b = blockIdx.x;
    __shared__ float f1l[64];
    __shared__ float f2[32];
    const int tid = threadIdx.x;
    f1l[tid] = f1[b * 64 + tid];
    __syncthreads();
    if (tid < 32) {
        float acc = b2[tid];
        const float* wr = w2 + (size_t)tid * 64;
#pragma unroll
        for (int k = 0; k < 64; ++k) acc += f1l[k] * wr[k];
        f2[tid] = fmaxf(acc, 0.f);
    }
    __syncthreads();
    if (tid == 0) {
        float y0 = b3[0], y1 = b3[1];
#pragma unroll
        for (int k = 0; k < 32; ++k) { y0 += f2[k] * w3[k]; y1 += f2[k] * w3[32 + k]; }
        const float m = fmaxf(y0, y1);
        const float lse = m + logf(expf(y0 - m) + expf(y1 - m));
        out[b * 2 + 0] = y0 - lse;
        out[b * 2 + 1] = y1 - lse;
    }
}

extern "C" void kernel_launch(void* const* d_in, const int* in_sizes, int n_in,
                              void* d_out, int out_size, void* d_ws, size_t ws_size,
                              hipStream_t stream) {
    const float* x    = (const float*)d_in[0];
    const float* ln_g = (const float*)d_in[1];
    const float* ln_b = (const float*)d_in[2];
    const float* w_l1 = (const float*)d_in[3];
    const float* b_l1 = (const float*)d_in[4];
    const float* w_l2 = (const float*)d_in[5];
    const float* b_l2 = (const float*)d_in[6];
    const float* w_c  = (const float*)d_in[7];
    const float* b_c  = (const float*)d_in[8];
    const float* w_f1 = (const float*)d_in[9];
    const float* b_f1 = (const float*)d_in[10];
    const float* w_f2 = (const float*)d_in[11];
    const float* b_f2 = (const float*)d_in[12];
    const float* w_f3 = (const float*)d_in[13];
    const float* b_f3 = (const float*)d_in[14];

    // Workspace (ushort offsets):
    //   xb0 (2 par) @0: 3,276,800 | xb1 (2 par): 3,735,552
    //   h0A | h1A | h0B | h1B: 15,777,792
    //   cst fp32 (5,120,000 f): 10,240,000 ush-equiv
    //   Wfrag 442,368 | Wc 73,728 | f1 8,192  -> total ~33.5M ush = 67.1 MB
    //   tail aliases: Hc -> h0B/h1B (dead); conv_out+pool -> cst (dead).
    ushort_t* wsu = (ushort_t*)d_ws;
    uint_t*   wsi = (uint_t*)d_ws;

    ushort_t* xb0 = wsu;                          // 2 * XB0T
    ushort_t* xb1 = xb0 + 2 * (size_t)XB0T;       // 2 * XB1T
    ushort_t* h0A = xb1 + 2 * (size_t)XB1T;
    ushort_t* h1A = h0A + HB0T;
    ushort_t* h0B = h1A + HB1T;
    ushort_t* h1B = h0B + HB0T;
    float*    cst = (float*)(h1B + HB1T);
    float*    conv_out = cst;
    float*    pool = cst + 2560000;
    ushort_t* Wfrag = (ushort_t*)cst + 10240000;
    ushort_t* Wc    = Wfrag + WFRAG_TOT;
    float*    f1    = (float*)(Wc + 73728);
    ushort_t* Hc    = h0B;

    // zero x-bufs (both parities, borders) + h-bufs (borders + h0 state)
    const size_t zt = 2 * (size_t)XB0T + 2 * (size_t)XB1T + 2 * (size_t)HPART;
    fill_zero_kernel<<<((int)(zt / 2) + 255) / 256, 256, 0, stream>>>(wsi, (int)(zt / 2));
    repack_w_kernel<<<(WFRAG_TOT + 255) / 256, 256, 0, stream>>>(w_l1, w_l2, Wfrag);
    repack_wc_kernel<<<(9 * 64 * 128 + 255) / 256, 256, 0, stream>>>(w_c, Wc);

    // LN for t=0 into parity-0 x-bufs
    ln_t_kernel<<<(B_ * NPIX + 255) / 256, 256, 0, stream>>>(x, ln_g, ln_b, xb0, xb1, 0);

    ushort_t* H0[2] = {h0A, h0B};
    ushort_t* H1[2] = {h1A, h1B};
    for (int t = 0; t < T_; ++t) {
        const int cur = t & 1, nxt = cur ^ 1;
        convlstm_mfma_kernel<<<dim3(NRG, B_, 2), 512, 0, stream>>>(
            x, ln_g, ln_b, xb0, xb1,
            H0[cur], H1[cur], H0[nxt], H1[nxt], Wfrag, b_l1, b_l2, cst, t);
    }
    // final h in parity-0 (A). Hc overwrites dead B half: zero it first.
    fill_zero_kernel<<<(HCTOT / 2 + 255) / 256, 256, 0, stream>>>((uint_t*)Hc, HCTOT / 2);
    combine_h_kernel<<<(B_ * NPIX * 128 + 255) / 256, 256, 0, stream>>>(h0A, h1A, Hc);
    conv_mfma_kernel<<<dim3(7, B_), 512, 0, stream>>>(Hc, Wc, b_c, conv_out);
    pool_kernel<<<(B_ * 64 * 144 + 255) / 256, 256, 0, stream>>>(conv_out, pool);
    fc1_kernel<<<1024, 256, 0, stream>>>(pool, w_f1, b_f1, f1);
    head2_kernel<<<B_, 64, 0, stream>>>(f1, w_f2, b_f2, w_f3, b_f3, (float*)d_out);
}